// Round 7
// baseline (229.498 us; speedup 1.0000x reference)
//
#include <hip/hip_runtime.h>
#include <math.h>

#define B_SZ 2
#define N_PTS 2048
#define DM 128
#define KNN 128
#define NLAYER 4
#define ROWS (B_SZ * N_PTS)
#define RBV 4
#define EPSLN 1e-5f

// ---------- reductions ----------
__device__ __forceinline__ float waveSum(float v) {
#pragma unroll
  for (int o = 32; o > 0; o >>= 1) v += __shfl_xor(v, o, 64);
  return v;
}
__device__ __forceinline__ float waveMax(float v) {
#pragma unroll
  for (int o = 32; o > 0; o >>= 1) v = fmaxf(v, __shfl_xor(v, o, 64));
  return v;
}
__device__ __forceinline__ float blockSum128(float v, float* s2, int t) {
  float w = waveSum(v);
  __syncthreads();
  if ((t & 63) == 0) s2[t >> 6] = w;
  __syncthreads();
  return s2[0] + s2[1];
}
__device__ __forceinline__ unsigned waveScanIncl(unsigned v, int lane) {
#pragma unroll
  for (int o = 1; o < 64; o <<= 1) {
    unsigned u = (unsigned)__shfl_up((int)v, o, 64);
    if (lane >= o) v += u;
  }
  return v;
}

// ---------- 1. knn ----------
__global__ __launch_bounds__(256) void knn_kernel(const float* __restrict__ xyz,
                                                  int* __restrict__ idx) {
  int row = blockIdx.x;
  int b = row >> 11, i = row & (N_PTS - 1);
  const float* xb = xyz + (size_t)b * N_PTS * 3;
  int tid = threadIdx.x;
  int lane = tid & 63, wid = tid >> 6;

  __shared__ unsigned hist[256];
  __shared__ unsigned wred[4];
  __shared__ unsigned sel[2];

  float xi = xb[i * 3 + 0], yi = xb[i * 3 + 1], zi = xb[i * 3 + 2];
  float sqi = xi * xi + yi * yi + zi * zi;

  float p[24];
  {
    const float4* xb4 = (const float4*)xb;
#pragma unroll
    for (int q = 0; q < 6; ++q) {
      float4 v = xb4[tid * 6 + q];
      p[q * 4 + 0] = v.x; p[q * 4 + 1] = v.y; p[q * 4 + 2] = v.z; p[q * 4 + 3] = v.w;
    }
  }
  unsigned key[8];
#pragma unroll
  for (int s = 0; s < 8; ++s) {
    float xj = p[s * 3 + 0], yj = p[s * 3 + 1], zj = p[s * 3 + 2];
    float d = sqi + xj * xj + yj * yj + zj * zj -
              2.0f * (xi * xj + yi * yj + zi * zj);
    unsigned u = __float_as_uint(d);
    key[s] = (u & 0x80000000u) ? ~u : (u | 0x80000000u);
  }

  unsigned prefix = 0;
  unsigned need = KNN;
  for (int shift = 24; shift >= 0; shift -= 8) {
    hist[tid] = 0;
    __syncthreads();
    if (shift == 24) {
#pragma unroll
      for (int s = 0; s < 8; ++s) {
        unsigned bin = key[s] >> 24;
        unsigned long long act = __ballot(1);
        while (act) {
          int src = __builtin_ctzll(act);
          unsigned bsel = (unsigned)__shfl((int)bin, src, 64);
          unsigned long long grp = __ballot(bin == bsel);
          if (lane == src)
            atomicAdd(&hist[bsel], (unsigned)__builtin_popcountll(grp));
          act &= ~grp;
        }
      }
    } else {
#pragma unroll
      for (int s = 0; s < 8; ++s) {
        unsigned k = key[s];
        if ((k >> (shift + 8)) == prefix)
          atomicAdd(&hist[(k >> shift) & 255u], 1u);
      }
    }
    __syncthreads();
    unsigned h = hist[tid];
    unsigned incl = waveScanIncl(h, lane);
    if (lane == 63) wred[wid] = incl;
    __syncthreads();
    unsigned offs = 0;
    for (int w = 0; w < wid; ++w) offs += wred[w];
    incl += offs;
    unsigned excl = incl - h;
    if (excl < need && need <= incl) { sel[0] = (unsigned)tid; sel[1] = need - excl; }
    __syncthreads();
    prefix = (prefix << 8) | sel[0];
    need = sel[1];
  }
  unsigned T = prefix;
  int need_eq = (int)need;

  unsigned clt = 0, ceq = 0;
#pragma unroll
  for (int s = 0; s < 8; ++s) {
    clt += (key[s] < T);
    ceq += (key[s] == T);
  }
  unsigned packed = clt | (ceq << 16);
  unsigned incl = waveScanIncl(packed, lane);
  if (lane == 63) wred[wid] = incl;
  __syncthreads();
  unsigned offs = 0;
  for (int w = 0; w < wid; ++w) offs += wred[w];
  unsigned totAll = wred[0] + wred[1] + wred[2] + wred[3];
  incl += offs;
  unsigned excl = incl - packed;
  int lt_base = (int)(excl & 0xFFFFu);
  int eq_base = (int)(excl >> 16);
  int total_lt = (int)(totAll & 0xFFFFu);

  int* orow = idx + (size_t)row * KNN;
  int lpos = 0, epos = 0;
#pragma unroll
  for (int s = 0; s < 8; ++s) {
    int j = tid * 8 + s;
    unsigned k = key[s];
    if (k < T) {
      orow[lt_base + lpos] = j; lpos++;
    } else if (k == T) {
      int r = eq_base + epos; epos++;
      if (r < need_eq) orow[total_lt + r] = j;
    }
  }
}

// ---------- 2. prep: rowsums + temb ----------
__global__ __launch_bounds__(128) void prep_kernel(
    const float* __restrict__ Wq, const float* __restrict__ bq,
    const float* __restrict__ Wk, const float* __restrict__ bk,
    const float* __restrict__ Wp2, const float* __restrict__ bp2,
    float* __restrict__ rs, float* __restrict__ ssum,
    const int* __restrict__ t, const float* __restrict__ tW1,
    const float* __restrict__ tb1, const float* __restrict__ tW2,
    const float* __restrict__ tb2, float* __restrict__ temb) {
  int blk = blockIdx.x, d = threadIdx.x;
  __shared__ float s2[2];
  __shared__ float emb[DM];
  __shared__ float h1[DM];
  if (blk < NLAYER) {
    int l = blk;
    const float* wq = Wq + (size_t)l * DM * DM;
    const float* wk = Wk + (size_t)l * DM * DM;
    const float* wp2 = Wp2 + (size_t)l * DM * DM;
    float a = 0.f, b = 0.f, c = 0.f;
    for (int j = 0; j < DM; ++j) {
      a += wq[d * DM + j];
      b += wk[d * DM + j];
      c += wp2[d * DM + j];
    }
    rs[l * 3 * DM + d] = a;
    rs[l * 3 * DM + DM + d] = b;
    rs[l * 3 * DM + 2 * DM + d] = c;
    float sq = blockSum128(bq[l * DM + d], s2, d);
    float sk = blockSum128(bk[l * DM + d], s2, d);
    float sp = blockSum128(bp2[l * DM + d], s2, d);
    if (d == 0) { ssum[l * 4 + 0] = sq; ssum[l * 4 + 1] = sk; ssum[l * 4 + 2] = sp; }
  } else {
    int b = blk - NLAYER;
    float tv = (float)t[b];
    float lg = logf(10000.0f);
    if (d < 64) {
      float f = expf(-lg * (float)d / 63.0f);
      emb[d] = sinf(tv * f);
    } else {
      float f = expf(-lg * (float)(d - 64) / 63.0f);
      emb[d] = cosf(tv * f);
    }
    __syncthreads();
    float acc = tb1[d];
    for (int j = 0; j < DM; ++j) acc = fmaf(emb[j], tW1[j * DM + d], acc);
    h1[d] = fmaxf(acc, 0.f);
    __syncthreads();
    float acc2 = tb2[d];
    for (int j = 0; j < DM; ++j) acc2 = fmaf(h1[j], tW2[j * DM + d], acc2);
    temb[b * DM + d] = acc2;
  }
}

// ---------- 3. V projection + q/k sums for layer 0 ----------
__global__ __launch_bounds__(256) void vqk_kernel(
    const float* __restrict__ feat, const float* __restrict__ Wv,
    const float* __restrict__ bv, const float* __restrict__ rs,
    const float* __restrict__ ssum, float* __restrict__ Vf,
    float* __restrict__ qsum, float* __restrict__ ksum) {
  int n0 = blockIdx.x * RBV;
  int t = threadIdx.x;
  int d = t & 127, half = t >> 7;
  __shared__ float fr[RBV][DM];
  __shared__ float part[RBV][DM];
  __shared__ float sA[2][RBV];
  __shared__ float sB[2][RBV];
#pragma unroll
  for (int u = 0; u < 2; ++u) {
    int r = half * 2 + u;
    fr[r][d] = feat[(size_t)(n0 + r) * DM + d];
  }
  __syncthreads();
  float acc[RBV] = {0.f, 0.f, 0.f, 0.f};
  int j0 = half * 64;
  for (int jj = 0; jj < 64; jj += 4) {
    int j = j0 + jj;
    float w0 = Wv[(j + 0) * DM + d], w1 = Wv[(j + 1) * DM + d];
    float w2 = Wv[(j + 2) * DM + d], w3 = Wv[(j + 3) * DM + d];
#pragma unroll
    for (int r = 0; r < RBV; ++r) {
      float4 f = *(const float4*)&fr[r][j];
      acc[r] = fmaf(f.x, w0, fmaf(f.y, w1, fmaf(f.z, w2, fmaf(f.w, w3, acc[r]))));
    }
  }
  if (half == 1) {
#pragma unroll
    for (int r = 0; r < RBV; ++r) part[r][d] = acc[r];
  }
  __syncthreads();
  if (half == 0) {
    float bvd = bv[d];
#pragma unroll
    for (int r = 0; r < RBV; ++r)
      Vf[(size_t)(n0 + r) * DM + d] = acc[r] + part[r][d] + bvd;
    int lane = t & 63, wid = (t >> 6) & 1;
    float rsq = rs[d], rsk = rs[DM + d];
#pragma unroll
    for (int r = 0; r < RBV; ++r) {
      float f = fr[r][d];
      float a = waveSum(f * rsq);
      float k = waveSum(f * rsk);
      if (lane == 0) { sA[wid][r] = a; sB[wid][r] = k; }
    }
  }
  __syncthreads();
  if (t < RBV) qsum[n0 + t] = sA[0][t] + sA[1][t] + ssum[0];
  if (t >= 64 && t < 64 + RBV) {
    int r = t - 64;
    ksum[n0 + r] = sB[0][r] + sB[1][r] + ssum[1];
  }
}

// ---------- 4. fused layer: 256 threads, 2 rows/block ----------
// Phases A/B: thread=(r=t>>7, u=t&127). GEMV phases: thread=(half=t>>7, d),
// 2-row register batch; combines are full-thread (each half finalizes its row).
template <int LAST>
__global__ __launch_bounds__(256, 4) void fused_layer_kernel(
    const float* __restrict__ xyz, const int* __restrict__ idx,
    const float* __restrict__ fin, const float* __restrict__ Vf_in,
    const float* __restrict__ qsum_in, const float* __restrict__ ksum_in,
    const float* __restrict__ Wp1, const float* __restrict__ bp1,
    const float* __restrict__ rsL, const float* __restrict__ ssL,
    const float* __restrict__ Wp2, const float* __restrict__ bp2,
    const float* __restrict__ Wproj, const float* __restrict__ bproj,
    const float* __restrict__ gamma, int l, float* __restrict__ fout,
    const float* __restrict__ Wv_n, const float* __restrict__ bv_n,
    const float* __restrict__ rs_n, const float* __restrict__ ss_n,
    float* __restrict__ Vf_out, float* __restrict__ qsum_out,
    float* __restrict__ ksum_out,
    const float* __restrict__ x_t, const float* __restrict__ temb,
    const float* __restrict__ nW1, const float* __restrict__ nb1,
    const float* __restrict__ ng1, const float* __restrict__ nbe1,
    const float* __restrict__ nW2, const float* __restrict__ nb2,
    const float* __restrict__ ng2, const float* __restrict__ nbe2,
    const float* __restrict__ nW3, const float* __restrict__ nb3,
    float* __restrict__ out) {
  int n0 = blockIdx.x * 2;
  int t = threadIdx.x;
  int r = t >> 7, u = t & 127;
  int w = t >> 6, lane = t & 63;
  int b = n0 >> 11;
  int row = n0 + r;
  int d = u;

  __shared__ float4 rel4[2][KNN];
  __shared__ int joff[2][KNN];
  __shared__ float hrow[2][DM];
  __shared__ float zz[2][DM];
  __shared__ float part[2][2][DM];  // [half][row][d]
  __shared__ float sred1[4];
  __shared__ float sred2[4];

  // ---- Phase A: rel + logits + per-row softmax; thread = (r, k=u)
  const float* xb = xyz + (size_t)b * N_PTS * 3;
  {
    int k = u;
    int i = row & (N_PTS - 1);
    float xi = xb[i * 3 + 0], yi = xb[i * 3 + 1], zi = xb[i * 3 + 2];
    int j = idx[(size_t)row * KNN + k];
    float rx = xi - xb[j * 3 + 0];
    float ry = yi - xb[j * 3 + 1];
    float rz = zi - xb[j * 3 + 2];

    const float4* W1x = (const float4*)Wp1;
    const float4* W1y = (const float4*)(Wp1 + DM);
    const float4* W1z = (const float4*)(Wp1 + 2 * DM);
    const float4* Bp = (const float4*)bp1;
    const float4* W2 = (const float4*)(rsL + 2 * DM);
    float acc0 = 0.f, acc1 = 0.f;
#pragma unroll 4
    for (int q = 0; q < DM / 4; q += 2) {
      float4 ax = W1x[q], ay = W1y[q], az = W1z[q], ab = Bp[q], c = W2[q];
      float h0v = fmaxf(fmaf(rx, ax.x, fmaf(ry, ay.x, fmaf(rz, az.x, ab.x))), 0.f);
      float h1v = fmaxf(fmaf(rx, ax.y, fmaf(ry, ay.y, fmaf(rz, az.y, ab.y))), 0.f);
      float h2v = fmaxf(fmaf(rx, ax.z, fmaf(ry, ay.z, fmaf(rz, az.z, ab.z))), 0.f);
      float h3v = fmaxf(fmaf(rx, ax.w, fmaf(ry, ay.w, fmaf(rz, az.w, ab.w))), 0.f);
      acc0 = fmaf(h0v, c.x, fmaf(h1v, c.y, fmaf(h2v, c.z, fmaf(h3v, c.w, acc0))));
      float4 ax2 = W1x[q + 1], ay2 = W1y[q + 1], az2 = W1z[q + 1],
             ab2 = Bp[q + 1], c2 = W2[q + 1];
      float h4 = fmaxf(fmaf(rx, ax2.x, fmaf(ry, ay2.x, fmaf(rz, az2.x, ab2.x))), 0.f);
      float h5 = fmaxf(fmaf(rx, ax2.y, fmaf(ry, ay2.y, fmaf(rz, az2.y, ab2.y))), 0.f);
      float h6 = fmaxf(fmaf(rx, ax2.z, fmaf(ry, ay2.z, fmaf(rz, az2.z, ab2.z))), 0.f);
      float h7 = fmaxf(fmaf(rx, ax2.w, fmaf(ry, ay2.w, fmaf(rz, az2.w, ab2.w))), 0.f);
      acc1 = fmaf(h4, c2.x, fmaf(h5, c2.y, fmaf(h6, c2.z, fmaf(h7, c2.w, acc1))));
    }
    float logit = qsum_in[row] - ksum_in[b * N_PTS + j] + (acc0 + acc1) + ssL[2];

    float m = waveMax(logit);
    if (lane == 0) sred1[w] = m;
    __syncthreads();
    m = fmaxf(sred1[r * 2], sred1[r * 2 + 1]);
    float e = __expf(logit - m);
    float sw = waveSum(e);
    if (lane == 0) sred2[w] = sw;
    __syncthreads();
    float ssm = sred2[r * 2] + sred2[r * 2 + 1];
    rel4[r][k] = make_float4(rx, ry, rz, e / ssm);
    joff[r][k] = j * (DM * 4);
  }
  __syncthreads();

  // ---- Phase B: aggregate; thread = (r, d)
  {
    float wdx = Wp1[d], wdy = Wp1[DM + d], wdz = Wp1[2 * DM + d], wdw = bp1[d];
    const char* vb = (const char*)(Vf_in + (size_t)b * N_PTS * DM + d);
    float ha0 = 0.f, ha1 = 0.f, va0 = 0.f, va1 = 0.f;
#pragma unroll 4
    for (int k = 0; k < KNN; k += 2) {
      float4 ra = rel4[r][k];
      float4 rb = rel4[r][k + 1];
      int ja = joff[r][k], jb = joff[r][k + 1];
      float Va = *(const float*)(vb + ja);
      float Vb = *(const float*)(vb + jb);
      float hA = fmaxf(fmaf(ra.x, wdx, fmaf(ra.y, wdy, fmaf(ra.z, wdz, wdw))), 0.f);
      float hB = fmaxf(fmaf(rb.x, wdx, fmaf(rb.y, wdy, fmaf(rb.z, wdz, wdw))), 0.f);
      ha0 = fmaf(ra.w, hA, ha0);
      ha1 = fmaf(rb.w, hB, ha1);
      va0 = fmaf(ra.w, Va, va0);
      va1 = fmaf(rb.w, Vb, va1);
    }
    hrow[r][d] = ha0 + ha1;
    zz[r][d] = va0 + va1;  // vagg
  }
  __syncthreads();

  // ---- Phase C1: z = vagg + hagg@Wp2 + bp2 (half-split, 2-row batch)
  {
    float a0 = 0.f, a1 = 0.f;
    int j0 = r * 64;
    for (int jj = 0; jj < 64; jj += 4) {
      int j = j0 + jj;
      float w0 = Wp2[(j + 0) * DM + d], w1 = Wp2[(j + 1) * DM + d];
      float w2 = Wp2[(j + 2) * DM + d], w3 = Wp2[(j + 3) * DM + d];
      float4 f0 = *(const float4*)&hrow[0][j];
      float4 f1 = *(const float4*)&hrow[1][j];
      a0 = fmaf(f0.x, w0, fmaf(f0.y, w1, fmaf(f0.z, w2, fmaf(f0.w, w3, a0))));
      a1 = fmaf(f1.x, w0, fmaf(f1.y, w1, fmaf(f1.z, w2, fmaf(f1.w, w3, a1))));
    }
    part[r][0][d] = a0; part[r][1][d] = a1;
  }
  __syncthreads();
  zz[r][d] += part[0][r][d] + part[1][r][d] + bp2[d];
  __syncthreads();

  // ---- Phase C2: fo = fin + gamma*(z@Wproj + bproj)
  {
    float a0 = 0.f, a1 = 0.f;
    int j0 = r * 64;
    for (int jj = 0; jj < 64; jj += 4) {
      int j = j0 + jj;
      float w0 = Wproj[(j + 0) * DM + d], w1 = Wproj[(j + 1) * DM + d];
      float w2 = Wproj[(j + 2) * DM + d], w3 = Wproj[(j + 3) * DM + d];
      float4 f0 = *(const float4*)&zz[0][j];
      float4 f1 = *(const float4*)&zz[1][j];
      a0 = fmaf(f0.x, w0, fmaf(f0.y, w1, fmaf(f0.z, w2, fmaf(f0.w, w3, a0))));
      a1 = fmaf(f1.x, w0, fmaf(f1.y, w1, fmaf(f1.z, w2, fmaf(f1.w, w3, a1))));
    }
    part[r][0][d] = a0; part[r][1][d] = a1;
  }
  __syncthreads();
  float fo;
  {
    float s = part[0][r][d] + part[1][r][d] + bproj[d];
    fo = fin[(size_t)row * DM + d] + gamma[l] * s;
    if (!LAST) fout[(size_t)row * DM + d] = fo;
    hrow[r][d] = fo;
  }
  __syncthreads();

  if constexpr (!LAST) {
    // ---- Phase D: next layer's V projection + q/k sums
    {
      float qp = waveSum(fo * rs_n[d]);
      float kp = waveSum(fo * rs_n[DM + d]);
      if (lane == 0) { sred1[w] = qp; sred2[w] = kp; }
    }
    {
      float a0 = 0.f, a1 = 0.f;
      int j0 = r * 64;
      for (int jj = 0; jj < 64; jj += 4) {
        int j = j0 + jj;
        float w0 = Wv_n[(j + 0) * DM + d], w1 = Wv_n[(j + 1) * DM + d];
        float w2 = Wv_n[(j + 2) * DM + d], w3 = Wv_n[(j + 3) * DM + d];
        float4 f0 = *(const float4*)&hrow[0][j];
        float4 f1 = *(const float4*)&hrow[1][j];
        a0 = fmaf(f0.x, w0, fmaf(f0.y, w1, fmaf(f0.z, w2, fmaf(f0.w, w3, a0))));
        a1 = fmaf(f1.x, w0, fmaf(f1.y, w1, fmaf(f1.z, w2, fmaf(f1.w, w3, a1))));
      }
      part[r][0][d] = a0; part[r][1][d] = a1;
    }
    __syncthreads();
    Vf_out[(size_t)row * DM + d] = part[0][r][d] + part[1][r][d] + bv_n[d];
    if (u == 0) qsum_out[row] = sred1[r * 2] + sred1[r * 2 + 1] + ss_n[0];
    if (u == 1) ksum_out[row] = sred2[r * 2] + sred2[r * 2 + 1] + ss_n[1];
  } else {
    // ---- Head: concat -> GEMV1 -> LN1 -> GEMV2 -> LN2 -> out proj
    __shared__ float h0s[2][260];
    __shared__ float souts[4][3];
    h0s[r][3 + d] = hrow[r][d];
    h0s[r][131 + d] = temb[b * DM + d];
    if (d < 3) h0s[r][d] = x_t[(size_t)row * 3 + d];
    if (d == 0) h0s[r][259] = 0.f;
    __syncthreads();

    // GEMV1: 259 inputs; half r covers [r*128, r*128+128), r==1 adds 256..258
    {
      float a0 = 0.f, a1 = 0.f;
      int j0 = r * 128;
      for (int jj = 0; jj < 128; jj += 4) {
        int j = j0 + jj;
        float w0 = nW1[(j + 0) * DM + d], w1 = nW1[(j + 1) * DM + d];
        float w2 = nW1[(j + 2) * DM + d], w3 = nW1[(j + 3) * DM + d];
        float4 f0 = *(const float4*)&h0s[0][j];
        float4 f1 = *(const float4*)&h0s[1][j];
        a0 = fmaf(f0.x, w0, fmaf(f0.y, w1, fmaf(f0.z, w2, fmaf(f0.w, w3, a0))));
        a1 = fmaf(f1.x, w0, fmaf(f1.y, w1, fmaf(f1.z, w2, fmaf(f1.w, w3, a1))));
      }
      if (r == 1) {
        for (int j = 256; j < 259; ++j) {
          float wv = nW1[j * DM + d];
          a0 = fmaf(h0s[0][j], wv, a0);
          a1 = fmaf(h0s[1][j], wv, a1);
        }
      }
      part[r][0][d] = a0; part[r][1][d] = a1;
    }
    __syncthreads();
    float acc1v = nb1[d] + part[0][r][d] + part[1][r][d];
    // LN1 (per-row over d)
    {
      float s1 = waveSum(acc1v), sq = waveSum(acc1v * acc1v);
      if (lane == 0) { sred1[w] = s1; sred2[w] = sq; }
      __syncthreads();
      float sx = sred1[r * 2] + sred1[r * 2 + 1];
      float sqq = sred2[r * 2] + sred2[r * 2 + 1];
      float m = sx * (1.0f / 128.0f);
      float var = sqq * (1.0f / 128.0f) - m * m;
      float y = (acc1v - m) * rsqrtf(var + EPSLN) * ng1[d] + nbe1[d];
      zz[r][d] = fmaxf(y, 0.f);
    }
    __syncthreads();
    // GEMV2: half covers 64 of 128
    {
      float a0 = 0.f, a1 = 0.f;
      int j0 = r * 64;
      for (int jj = 0; jj < 64; jj += 4) {
        int j = j0 + jj;
        float w0 = nW2[(j + 0) * DM + d], w1 = nW2[(j + 1) * DM + d];
        float w2 = nW2[(j + 2) * DM + d], w3 = nW2[(j + 3) * DM + d];
        float4 f0 = *(const float4*)&zz[0][j];
        float4 f1 = *(const float4*)&zz[1][j];
        a0 = fmaf(f0.x, w0, fmaf(f0.y, w1, fmaf(f0.z, w2, fmaf(f0.w, w3, a0))));
        a1 = fmaf(f1.x, w0, fmaf(f1.y, w1, fmaf(f1.z, w2, fmaf(f1.w, w3, a1))));
      }
      part[r][0][d] = a0; part[r][1][d] = a1;
    }
    __syncthreads();
    float acc2v = nb2[d] + part[0][r][d] + part[1][r][d];
    // LN2 + 128->3 projection
    {
      float s1 = waveSum(acc2v), sq = waveSum(acc2v * acc2v);
      if (lane == 0) { sred1[w] = s1; sred2[w] = sq; }
      __syncthreads();
      float sx = sred1[r * 2] + sred1[r * 2 + 1];
      float sqq = sred2[r * 2] + sred2[r * 2 + 1];
      float m = sx * (1.0f / 128.0f);
      float var = sqq * (1.0f / 128.0f) - m * m;
      float y = (acc2v - m) * rsqrtf(var + EPSLN) * ng2[d] + nbe2[d];
      float y2 = fmaxf(y, 0.f);
      float p0 = waveSum(y2 * nW3[d * 3 + 0]);
      float p1 = waveSum(y2 * nW3[d * 3 + 1]);
      float p2 = waveSum(y2 * nW3[d * 3 + 2]);
      if (lane == 0) { souts[w][0] = p0; souts[w][1] = p1; souts[w][2] = p2; }
    }
    __syncthreads();
    if (u < 3)
      out[(size_t)row * 3 + u] =
          souts[r * 2][u] + souts[r * 2 + 1][u] + nb3[u];
  }
}

// ---------- launch ----------
extern "C" void kernel_launch(void* const* d_in, const int* in_sizes, int n_in,
                              void* d_out, int out_size, void* d_ws,
                              size_t ws_size, hipStream_t stream) {
  const float* xyz = (const float*)d_in[0];
  const float* feat = (const float*)d_in[1];
  const float* x_t = (const float*)d_in[2];
  const int* t = (const int*)d_in[3];
  const float* Wq = (const float*)d_in[4];
  const float* bq = (const float*)d_in[5];
  const float* Wk = (const float*)d_in[6];
  const float* bk = (const float*)d_in[7];
  const float* Wv = (const float*)d_in[8];
  const float* bv = (const float*)d_in[9];
  const float* Wp1 = (const float*)d_in[10];
  const float* bp1 = (const float*)d_in[11];
  const float* Wp2 = (const float*)d_in[12];
  const float* bp2 = (const float*)d_in[13];
  const float* gamma = (const float*)d_in[14];
  const float* Wproj = (const float*)d_in[15];
  const float* bproj = (const float*)d_in[16];
  const float* tW1 = (const float*)d_in[17];
  const float* tb1 = (const float*)d_in[18];
  const float* tW2 = (const float*)d_in[19];
  const float* tb2 = (const float*)d_in[20];
  const float* nW1 = (const float*)d_in[21];
  const float* nb1 = (const float*)d_in[22];
  const float* ng1 = (const float*)d_in[23];
  const float* nbe1 = (const float*)d_in[24];
  const float* nW2 = (const float*)d_in[25];
  const float* nb2 = (const float*)d_in[26];
  const float* ng2 = (const float*)d_in[27];
  const float* nbe2 = (const float*)d_in[28];
  const float* nW3 = (const float*)d_in[29];
  const float* nb3 = (const float*)d_in[30];
  float* out = (float*)d_out;

  char* ws = (char*)d_ws;
  size_t off = 0;
  int* w_idx = (int*)(ws + off); off += (size_t)ROWS * KNN * 4;
  float* w_VfA = (float*)(ws + off); off += (size_t)ROWS * DM * 4;
  float* w_VfB = (float*)(ws + off); off += (size_t)ROWS * DM * 4;
  float* w_qsA = (float*)(ws + off); off += (size_t)ROWS * 4;
  float* w_ksA = (float*)(ws + off); off += (size_t)ROWS * 4;
  float* w_qsB = (float*)(ws + off); off += (size_t)ROWS * 4;
  float* w_ksB = (float*)(ws + off); off += (size_t)ROWS * 4;
  float* w_fA = (float*)(ws + off); off += (size_t)ROWS * DM * 4;
  float* w_fB = (float*)(ws + off); off += (size_t)ROWS * DM * 4;
  float* w_temb = (float*)(ws + off); off += (size_t)B_SZ * DM * 4;
  float* w_rs = (float*)(ws + off); off += (size_t)NLAYER * 3 * DM * 4;
  float* w_ssum = (float*)(ws + off); off += (size_t)NLAYER * 4 * 4;

  knn_kernel<<<ROWS, 256, 0, stream>>>(xyz, w_idx);
  prep_kernel<<<NLAYER + B_SZ, 128, 0, stream>>>(Wq, bq, Wk, bk, Wp2, bp2,
                                                 w_rs, w_ssum, t, tW1, tb1,
                                                 tW2, tb2, w_temb);
  vqk_kernel<<<ROWS / RBV, 256, 0, stream>>>(feat, Wv, bv, w_rs, w_ssum,
                                             w_VfA, w_qsA, w_ksA);

  const float* fins[4] = {feat, w_fA, w_fB, w_fA};
  float* fouts[4] = {w_fA, w_fB, w_fA, w_fB};
  const float* VfIn[4] = {w_VfA, w_VfB, w_VfA, w_VfB};
  float* VfOut[4] = {w_VfB, w_VfA, w_VfB, w_VfA};
  const float* qsIn[4] = {w_qsA, w_qsB, w_qsA, w_qsB};
  float* qsOut[4] = {w_qsB, w_qsA, w_qsB, w_qsA};
  const float* ksIn[4] = {w_ksA, w_ksB, w_ksA, w_ksB};
  float* ksOut[4] = {w_ksB, w_ksA, w_ksB, w_ksA};

  for (int l = 0; l < NLAYER; ++l) {
    const float* rsL = w_rs + (size_t)l * 3 * DM;
    const float* ssL = w_ssum + (size_t)l * 4;
    int ln = (l + 1 < NLAYER) ? (l + 1) : l;
    const float* rsN = w_rs + (size_t)ln * 3 * DM;
    const float* ssN = w_ssum + (size_t)ln * 4;
    if (l < NLAYER - 1) {
      fused_layer_kernel<0><<<ROWS / 2, 256, 0, stream>>>(
          xyz, w_idx, fins[l], VfIn[l], qsIn[l], ksIn[l],
          Wp1 + (size_t)l * 3 * DM, bp1 + (size_t)l * DM, rsL, ssL,
          Wp2 + (size_t)l * DM * DM, bp2 + (size_t)l * DM,
          Wproj + (size_t)l * DM * DM, bproj + (size_t)l * DM, gamma, l,
          fouts[l], Wv + (size_t)ln * DM * DM, bv + (size_t)ln * DM, rsN, ssN,
          VfOut[l], qsOut[l], ksOut[l], x_t, w_temb, nW1, nb1, ng1, nbe1, nW2,
          nb2, ng2, nbe2, nW3, nb3, out);
    } else {
      fused_layer_kernel<1><<<ROWS / 2, 256, 0, stream>>>(
          xyz, w_idx, fins[l], VfIn[l], qsIn[l], ksIn[l],
          Wp1 + (size_t)l * 3 * DM, bp1 + (size_t)l * DM, rsL, ssL,
          Wp2 + (size_t)l * DM * DM, bp2 + (size_t)l * DM,
          Wproj + (size_t)l * DM * DM, bproj + (size_t)l * DM, gamma, l,
          fouts[l], Wv + (size_t)ln * DM * DM, bv + (size_t)ln * DM, rsN, ssN,
          VfOut[l], qsOut[l], ksOut[l], x_t, w_temb, nW1, nb1, ng1, nbe1, nW2,
          nb2, ng2, nbe2, nW3, nb3, out);
    }
  }
}

// Round 8
// 212.542 us; speedup vs baseline: 1.0798x; 1.0798x over previous
//
#include <hip/hip_runtime.h>
#include <math.h>

#define B_SZ 2
#define N_PTS 2048
#define DM 128
#define KNN 128
#define NLAYER 4
#define ROWS (B_SZ * N_PTS)
#define RBV 4
#define EPSLN 1e-5f

// ---------- reductions ----------
__device__ __forceinline__ float waveSum(float v) {
#pragma unroll
  for (int o = 32; o > 0; o >>= 1) v += __shfl_xor(v, o, 64);
  return v;
}
__device__ __forceinline__ float waveMax(float v) {
#pragma unroll
  for (int o = 32; o > 0; o >>= 1) v = fmaxf(v, __shfl_xor(v, o, 64));
  return v;
}
__device__ __forceinline__ float blockSum128(float v, float* s2, int t) {
  float w = waveSum(v);
  __syncthreads();
  if ((t & 63) == 0) s2[t >> 6] = w;
  __syncthreads();
  return s2[0] + s2[1];
}
__device__ __forceinline__ unsigned waveScanIncl(unsigned v, int lane) {
#pragma unroll
  for (int o = 1; o < 64; o <<= 1) {
    unsigned u = (unsigned)__shfl_up((int)v, o, 64);
    if (lane >= o) v += u;
  }
  return v;
}

// ---------- 1. knn ----------
__global__ __launch_bounds__(256) void knn_kernel(const float* __restrict__ xyz,
                                                  int* __restrict__ idx) {
  int row = blockIdx.x;
  int b = row >> 11, i = row & (N_PTS - 1);
  const float* xb = xyz + (size_t)b * N_PTS * 3;
  int tid = threadIdx.x;
  int lane = tid & 63, wid = tid >> 6;

  __shared__ unsigned hist[256];
  __shared__ unsigned wred[4];
  __shared__ unsigned sel[2];

  float xi = xb[i * 3 + 0], yi = xb[i * 3 + 1], zi = xb[i * 3 + 2];
  float sqi = xi * xi + yi * yi + zi * zi;

  float p[24];
  {
    const float4* xb4 = (const float4*)xb;
#pragma unroll
    for (int q = 0; q < 6; ++q) {
      float4 v = xb4[tid * 6 + q];
      p[q * 4 + 0] = v.x; p[q * 4 + 1] = v.y; p[q * 4 + 2] = v.z; p[q * 4 + 3] = v.w;
    }
  }
  unsigned key[8];
#pragma unroll
  for (int s = 0; s < 8; ++s) {
    float xj = p[s * 3 + 0], yj = p[s * 3 + 1], zj = p[s * 3 + 2];
    float d = sqi + xj * xj + yj * yj + zj * zj -
              2.0f * (xi * xj + yi * yj + zi * zj);
    unsigned u = __float_as_uint(d);
    key[s] = (u & 0x80000000u) ? ~u : (u | 0x80000000u);
  }

  unsigned prefix = 0;
  unsigned need = KNN;
  for (int shift = 24; shift >= 0; shift -= 8) {
    hist[tid] = 0;
    __syncthreads();
    if (shift == 24) {
#pragma unroll
      for (int s = 0; s < 8; ++s) {
        unsigned bin = key[s] >> 24;
        unsigned long long act = __ballot(1);
        while (act) {
          int src = __builtin_ctzll(act);
          unsigned bsel = (unsigned)__shfl((int)bin, src, 64);
          unsigned long long grp = __ballot(bin == bsel);
          if (lane == src)
            atomicAdd(&hist[bsel], (unsigned)__builtin_popcountll(grp));
          act &= ~grp;
        }
      }
    } else {
#pragma unroll
      for (int s = 0; s < 8; ++s) {
        unsigned k = key[s];
        if ((k >> (shift + 8)) == prefix)
          atomicAdd(&hist[(k >> shift) & 255u], 1u);
      }
    }
    __syncthreads();
    unsigned h = hist[tid];
    unsigned incl = waveScanIncl(h, lane);
    if (lane == 63) wred[wid] = incl;
    __syncthreads();
    unsigned offs = 0;
    for (int w = 0; w < wid; ++w) offs += wred[w];
    incl += offs;
    unsigned excl = incl - h;
    if (excl < need && need <= incl) { sel[0] = (unsigned)tid; sel[1] = need - excl; }
    __syncthreads();
    prefix = (prefix << 8) | sel[0];
    need = sel[1];
  }
  unsigned T = prefix;
  int need_eq = (int)need;

  unsigned clt = 0, ceq = 0;
#pragma unroll
  for (int s = 0; s < 8; ++s) {
    clt += (key[s] < T);
    ceq += (key[s] == T);
  }
  unsigned packed = clt | (ceq << 16);
  unsigned incl = waveScanIncl(packed, lane);
  if (lane == 63) wred[wid] = incl;
  __syncthreads();
  unsigned offs = 0;
  for (int w = 0; w < wid; ++w) offs += wred[w];
  unsigned totAll = wred[0] + wred[1] + wred[2] + wred[3];
  incl += offs;
  unsigned excl = incl - packed;
  int lt_base = (int)(excl & 0xFFFFu);
  int eq_base = (int)(excl >> 16);
  int total_lt = (int)(totAll & 0xFFFFu);

  int* orow = idx + (size_t)row * KNN;
  int lpos = 0, epos = 0;
#pragma unroll
  for (int s = 0; s < 8; ++s) {
    int j = tid * 8 + s;
    unsigned k = key[s];
    if (k < T) {
      orow[lt_base + lpos] = j; lpos++;
    } else if (k == T) {
      int r = eq_base + epos; epos++;
      if (r < need_eq) orow[total_lt + r] = j;
    }
  }
}

// ---------- 2. prep: rowsums + temb ----------
__global__ __launch_bounds__(128) void prep_kernel(
    const float* __restrict__ Wq, const float* __restrict__ bq,
    const float* __restrict__ Wk, const float* __restrict__ bk,
    const float* __restrict__ Wp2, const float* __restrict__ bp2,
    float* __restrict__ rs, float* __restrict__ ssum,
    const int* __restrict__ t, const float* __restrict__ tW1,
    const float* __restrict__ tb1, const float* __restrict__ tW2,
    const float* __restrict__ tb2, float* __restrict__ temb) {
  int blk = blockIdx.x, d = threadIdx.x;
  __shared__ float s2[2];
  __shared__ float emb[DM];
  __shared__ float h1[DM];
  if (blk < NLAYER) {
    int l = blk;
    const float* wq = Wq + (size_t)l * DM * DM;
    const float* wk = Wk + (size_t)l * DM * DM;
    const float* wp2 = Wp2 + (size_t)l * DM * DM;
    float a = 0.f, b = 0.f, c = 0.f;
    for (int j = 0; j < DM; ++j) {
      a += wq[d * DM + j];
      b += wk[d * DM + j];
      c += wp2[d * DM + j];
    }
    rs[l * 3 * DM + d] = a;
    rs[l * 3 * DM + DM + d] = b;
    rs[l * 3 * DM + 2 * DM + d] = c;
    float sq = blockSum128(bq[l * DM + d], s2, d);
    float sk = blockSum128(bk[l * DM + d], s2, d);
    float sp = blockSum128(bp2[l * DM + d], s2, d);
    if (d == 0) { ssum[l * 4 + 0] = sq; ssum[l * 4 + 1] = sk; ssum[l * 4 + 2] = sp; }
  } else {
    int b = blk - NLAYER;
    float tv = (float)t[b];
    float lg = logf(10000.0f);
    if (d < 64) {
      float f = expf(-lg * (float)d / 63.0f);
      emb[d] = sinf(tv * f);
    } else {
      float f = expf(-lg * (float)(d - 64) / 63.0f);
      emb[d] = cosf(tv * f);
    }
    __syncthreads();
    float acc = tb1[d];
    for (int j = 0; j < DM; ++j) acc = fmaf(emb[j], tW1[j * DM + d], acc);
    h1[d] = fmaxf(acc, 0.f);
    __syncthreads();
    float acc2 = tb2[d];
    for (int j = 0; j < DM; ++j) acc2 = fmaf(h1[j], tW2[j * DM + d], acc2);
    temb[b * DM + d] = acc2;
  }
}

// ---------- 3. V projection + q/k sums for layer 0 ----------
__global__ __launch_bounds__(256) void vqk_kernel(
    const float* __restrict__ feat, const float* __restrict__ Wv,
    const float* __restrict__ bv, const float* __restrict__ rs,
    const float* __restrict__ ssum, float* __restrict__ Vf,
    float* __restrict__ qsum, float* __restrict__ ksum) {
  int n0 = blockIdx.x * RBV;
  int t = threadIdx.x;
  int d = t & 127, half = t >> 7;
  __shared__ float fr[RBV][DM];
  __shared__ float part[RBV][DM];
  __shared__ float sA[2][RBV];
  __shared__ float sB[2][RBV];
#pragma unroll
  for (int u = 0; u < 2; ++u) {
    int r = half * 2 + u;
    fr[r][d] = feat[(size_t)(n0 + r) * DM + d];
  }
  __syncthreads();
  float acc[RBV] = {0.f, 0.f, 0.f, 0.f};
  int j0 = half * 64;
  for (int jj = 0; jj < 64; jj += 4) {
    int j = j0 + jj;
    float w0 = Wv[(j + 0) * DM + d], w1 = Wv[(j + 1) * DM + d];
    float w2 = Wv[(j + 2) * DM + d], w3 = Wv[(j + 3) * DM + d];
#pragma unroll
    for (int r = 0; r < RBV; ++r) {
      float4 f = *(const float4*)&fr[r][j];
      acc[r] = fmaf(f.x, w0, fmaf(f.y, w1, fmaf(f.z, w2, fmaf(f.w, w3, acc[r]))));
    }
  }
  if (half == 1) {
#pragma unroll
    for (int r = 0; r < RBV; ++r) part[r][d] = acc[r];
  }
  __syncthreads();
  if (half == 0) {
    float bvd = bv[d];
#pragma unroll
    for (int r = 0; r < RBV; ++r)
      Vf[(size_t)(n0 + r) * DM + d] = acc[r] + part[r][d] + bvd;
    int lane = t & 63, wid = (t >> 6) & 1;
    float rsq = rs[d], rsk = rs[DM + d];
#pragma unroll
    for (int r = 0; r < RBV; ++r) {
      float f = fr[r][d];
      float a = waveSum(f * rsq);
      float k = waveSum(f * rsk);
      if (lane == 0) { sA[wid][r] = a; sB[wid][r] = k; }
    }
  }
  __syncthreads();
  if (t < RBV) qsum[n0 + t] = sA[0][t] + sA[1][t] + ssum[0];
  if (t >= 64 && t < 64 + RBV) {
    int r = t - 64;
    ksum[n0 + r] = sB[0][r] + sB[1][r] + ssum[1];
  }
}

// ---------- 4. fused layer: 512 threads, 4 rows/block ----------
// Phases A/B: thread=(r=t>>7, u=t&127). GEMV phases: thread=(quarter=t>>7, d),
// 4-row register batch; combines fully parallel (quarter r finalizes row r).
template <int LAST>
__global__ __launch_bounds__(512, 2) void fused_layer_kernel(
    const float* __restrict__ xyz, const int* __restrict__ idx,
    const float* __restrict__ fin, const float* __restrict__ Vf_in,
    const float* __restrict__ qsum_in, const float* __restrict__ ksum_in,
    const float* __restrict__ Wp1, const float* __restrict__ bp1,
    const float* __restrict__ rsL, const float* __restrict__ ssL,
    const float* __restrict__ Wp2, const float* __restrict__ bp2,
    const float* __restrict__ Wproj, const float* __restrict__ bproj,
    const float* __restrict__ gamma, int l, float* __restrict__ fout,
    const float* __restrict__ Wv_n, const float* __restrict__ bv_n,
    const float* __restrict__ rs_n, const float* __restrict__ ss_n,
    float* __restrict__ Vf_out, float* __restrict__ qsum_out,
    float* __restrict__ ksum_out,
    const float* __restrict__ x_t, const float* __restrict__ temb,
    const float* __restrict__ nW1, const float* __restrict__ nb1,
    const float* __restrict__ ng1, const float* __restrict__ nbe1,
    const float* __restrict__ nW2, const float* __restrict__ nb2,
    const float* __restrict__ ng2, const float* __restrict__ nbe2,
    const float* __restrict__ nW3, const float* __restrict__ nb3,
    float* __restrict__ out) {
  int n0 = blockIdx.x * 4;
  int t = threadIdx.x;
  int r = t >> 7, u = t & 127;
  int w = t >> 6, lane = t & 63;
  int b = n0 >> 11;
  int row = n0 + r;
  int d = u;

  __shared__ float4 rel4[4][KNN];
  __shared__ int joff[4][KNN];
  __shared__ float hrow[4][DM];    // hagg, later fo (fr)
  __shared__ float zz[4][DM];      // vagg -> z, later LN buffers
  __shared__ float part[4][4][DM]; // [quarter][row][d] GEMV partials
  __shared__ float sred1[8];
  __shared__ float sred2[8];

  // ---- Phase A: rel + logits + per-row softmax; thread = (r, k=u)
  const float* xb = xyz + (size_t)b * N_PTS * 3;
  {
    int k = u;
    int i = row & (N_PTS - 1);
    float xi = xb[i * 3 + 0], yi = xb[i * 3 + 1], zi = xb[i * 3 + 2];
    int j = idx[(size_t)row * KNN + k];
    float rx = xi - xb[j * 3 + 0];
    float ry = yi - xb[j * 3 + 1];
    float rz = zi - xb[j * 3 + 2];

    const float4* W1x = (const float4*)Wp1;
    const float4* W1y = (const float4*)(Wp1 + DM);
    const float4* W1z = (const float4*)(Wp1 + 2 * DM);
    const float4* Bp = (const float4*)bp1;
    const float4* W2 = (const float4*)(rsL + 2 * DM);
    float acc0 = 0.f, acc1 = 0.f;
#pragma unroll 4
    for (int q = 0; q < DM / 4; q += 2) {
      float4 ax = W1x[q], ay = W1y[q], az = W1z[q], ab = Bp[q], c = W2[q];
      float h0v = fmaxf(fmaf(rx, ax.x, fmaf(ry, ay.x, fmaf(rz, az.x, ab.x))), 0.f);
      float h1v = fmaxf(fmaf(rx, ax.y, fmaf(ry, ay.y, fmaf(rz, az.y, ab.y))), 0.f);
      float h2v = fmaxf(fmaf(rx, ax.z, fmaf(ry, ay.z, fmaf(rz, az.z, ab.z))), 0.f);
      float h3v = fmaxf(fmaf(rx, ax.w, fmaf(ry, ay.w, fmaf(rz, az.w, ab.w))), 0.f);
      acc0 = fmaf(h0v, c.x, fmaf(h1v, c.y, fmaf(h2v, c.z, fmaf(h3v, c.w, acc0))));
      float4 ax2 = W1x[q + 1], ay2 = W1y[q + 1], az2 = W1z[q + 1],
             ab2 = Bp[q + 1], c2 = W2[q + 1];
      float h4 = fmaxf(fmaf(rx, ax2.x, fmaf(ry, ay2.x, fmaf(rz, az2.x, ab2.x))), 0.f);
      float h5 = fmaxf(fmaf(rx, ax2.y, fmaf(ry, ay2.y, fmaf(rz, az2.y, ab2.y))), 0.f);
      float h6 = fmaxf(fmaf(rx, ax2.z, fmaf(ry, ay2.z, fmaf(rz, az2.z, ab2.z))), 0.f);
      float h7 = fmaxf(fmaf(rx, ax2.w, fmaf(ry, ay2.w, fmaf(rz, az2.w, ab2.w))), 0.f);
      acc1 = fmaf(h4, c2.x, fmaf(h5, c2.y, fmaf(h6, c2.z, fmaf(h7, c2.w, acc1))));
    }
    float logit = qsum_in[row] - ksum_in[b * N_PTS + j] + (acc0 + acc1) + ssL[2];

    float m = waveMax(logit);
    if (lane == 0) sred1[w] = m;
    __syncthreads();
    m = fmaxf(sred1[r * 2], sred1[r * 2 + 1]);
    float e = __expf(logit - m);
    float sw = waveSum(e);
    if (lane == 0) sred2[w] = sw;
    __syncthreads();
    float ssm = sred2[r * 2] + sred2[r * 2 + 1];
    rel4[r][k] = make_float4(rx, ry, rz, e / ssm);
    joff[r][k] = j * (DM * 4);
  }
  __syncthreads();

  // ---- Phase B: aggregate; thread = (r, d)
  {
    float wdx = Wp1[d], wdy = Wp1[DM + d], wdz = Wp1[2 * DM + d], wdw = bp1[d];
    const char* vb = (const char*)(Vf_in + (size_t)b * N_PTS * DM + d);
    float ha0 = 0.f, ha1 = 0.f, va0 = 0.f, va1 = 0.f;
#pragma unroll 4
    for (int k = 0; k < KNN; k += 2) {
      float4 ra = rel4[r][k];
      float4 rb = rel4[r][k + 1];
      int ja = joff[r][k], jb = joff[r][k + 1];
      float Va = *(const float*)(vb + ja);
      float Vb = *(const float*)(vb + jb);
      float hA = fmaxf(fmaf(ra.x, wdx, fmaf(ra.y, wdy, fmaf(ra.z, wdz, wdw))), 0.f);
      float hB = fmaxf(fmaf(rb.x, wdx, fmaf(rb.y, wdy, fmaf(rb.z, wdz, wdw))), 0.f);
      ha0 = fmaf(ra.w, hA, ha0);
      ha1 = fmaf(rb.w, hB, ha1);
      va0 = fmaf(ra.w, Va, va0);
      va1 = fmaf(rb.w, Vb, va1);
    }
    hrow[r][d] = ha0 + ha1;
    zz[r][d] = va0 + va1;  // vagg
  }
  __syncthreads();

  // ---- Phase C1: z = vagg + hagg@Wp2 + bp2  (quarter-split, 4-row batch)
  {
    float a0 = 0.f, a1 = 0.f, a2 = 0.f, a3 = 0.f;
    int j0 = r * 32;
    for (int jj = 0; jj < 32; jj += 4) {
      int j = j0 + jj;
      float w0 = Wp2[(j + 0) * DM + d], w1 = Wp2[(j + 1) * DM + d];
      float w2 = Wp2[(j + 2) * DM + d], w3 = Wp2[(j + 3) * DM + d];
      float4 f0 = *(const float4*)&hrow[0][j];
      float4 f1 = *(const float4*)&hrow[1][j];
      float4 f2 = *(const float4*)&hrow[2][j];
      float4 f3 = *(const float4*)&hrow[3][j];
      a0 = fmaf(f0.x, w0, fmaf(f0.y, w1, fmaf(f0.z, w2, fmaf(f0.w, w3, a0))));
      a1 = fmaf(f1.x, w0, fmaf(f1.y, w1, fmaf(f1.z, w2, fmaf(f1.w, w3, a1))));
      a2 = fmaf(f2.x, w0, fmaf(f2.y, w1, fmaf(f2.z, w2, fmaf(f2.w, w3, a2))));
      a3 = fmaf(f3.x, w0, fmaf(f3.y, w1, fmaf(f3.z, w2, fmaf(f3.w, w3, a3))));
    }
    part[r][0][d] = a0; part[r][1][d] = a1; part[r][2][d] = a2; part[r][3][d] = a3;
  }
  __syncthreads();
  // parallel combine: quarter r finalizes row r
  zz[r][d] += part[0][r][d] + part[1][r][d] + part[2][r][d] + part[3][r][d] +
              bp2[d];
  __syncthreads();

  // ---- Phase C2: fo = fin + gamma*(z@Wproj + bproj)
  {
    float a0 = 0.f, a1 = 0.f, a2 = 0.f, a3 = 0.f;
    int j0 = r * 32;
    for (int jj = 0; jj < 32; jj += 4) {
      int j = j0 + jj;
      float w0 = Wproj[(j + 0) * DM + d], w1 = Wproj[(j + 1) * DM + d];
      float w2 = Wproj[(j + 2) * DM + d], w3 = Wproj[(j + 3) * DM + d];
      float4 f0 = *(const float4*)&zz[0][j];
      float4 f1 = *(const float4*)&zz[1][j];
      float4 f2 = *(const float4*)&zz[2][j];
      float4 f3 = *(const float4*)&zz[3][j];
      a0 = fmaf(f0.x, w0, fmaf(f0.y, w1, fmaf(f0.z, w2, fmaf(f0.w, w3, a0))));
      a1 = fmaf(f1.x, w0, fmaf(f1.y, w1, fmaf(f1.z, w2, fmaf(f1.w, w3, a1))));
      a2 = fmaf(f2.x, w0, fmaf(f2.y, w1, fmaf(f2.z, w2, fmaf(f2.w, w3, a2))));
      a3 = fmaf(f3.x, w0, fmaf(f3.y, w1, fmaf(f3.z, w2, fmaf(f3.w, w3, a3))));
    }
    part[r][0][d] = a0; part[r][1][d] = a1; part[r][2][d] = a2; part[r][3][d] = a3;
  }
  __syncthreads();
  // parallel combine + store: quarter r finalizes row r
  float fo;
  {
    float s = part[0][r][d] + part[1][r][d] + part[2][r][d] + part[3][r][d] +
              bproj[d];
    fo = fin[(size_t)row * DM + d] + gamma[l] * s;
    if (!LAST) fout[(size_t)row * DM + d] = fo;
    hrow[r][d] = fo;  // fr for next phase
  }
  __syncthreads();

  if constexpr (!LAST) {
    // ---- Phase D: next layer's V projection + q/k sums
    {
      float qp = waveSum(fo * rs_n[d]);
      float kp = waveSum(fo * rs_n[DM + d]);
      if (lane == 0) { sred1[w] = qp; sred2[w] = kp; }
    }
    {
      float a0 = 0.f, a1 = 0.f, a2 = 0.f, a3 = 0.f;
      int j0 = r * 32;
      for (int jj = 0; jj < 32; jj += 4) {
        int j = j0 + jj;
        float w0 = Wv_n[(j + 0) * DM + d], w1 = Wv_n[(j + 1) * DM + d];
        float w2 = Wv_n[(j + 2) * DM + d], w3 = Wv_n[(j + 3) * DM + d];
        float4 f0 = *(const float4*)&hrow[0][j];
        float4 f1 = *(const float4*)&hrow[1][j];
        float4 f2 = *(const float4*)&hrow[2][j];
        float4 f3 = *(const float4*)&hrow[3][j];
        a0 = fmaf(f0.x, w0, fmaf(f0.y, w1, fmaf(f0.z, w2, fmaf(f0.w, w3, a0))));
        a1 = fmaf(f1.x, w0, fmaf(f1.y, w1, fmaf(f1.z, w2, fmaf(f1.w, w3, a1))));
        a2 = fmaf(f2.x, w0, fmaf(f2.y, w1, fmaf(f2.z, w2, fmaf(f2.w, w3, a2))));
        a3 = fmaf(f3.x, w0, fmaf(f3.y, w1, fmaf(f3.z, w2, fmaf(f3.w, w3, a3))));
      }
      part[r][0][d] = a0; part[r][1][d] = a1; part[r][2][d] = a2; part[r][3][d] = a3;
    }
    __syncthreads();
    // parallel combine + store: quarter r finalizes row r
    Vf_out[(size_t)row * DM + d] = part[0][r][d] + part[1][r][d] +
                                   part[2][r][d] + part[3][r][d] + bv_n[d];
    if (u == 0) qsum_out[row] = sred1[r * 2] + sred1[r * 2 + 1] + ss_n[0];
    if (u == 1) ksum_out[row] = sred2[r * 2] + sred2[r * 2 + 1] + ss_n[1];
  } else {
    // ---- Head: concat -> GEMV1 -> LN1 -> GEMV2 -> LN2 -> out proj
    __shared__ float h0s[4][260];
    __shared__ float souts[8][3];
    h0s[r][3 + d] = hrow[r][d];
    h0s[r][131 + d] = temb[b * DM + d];
    if (d < 3) h0s[r][d] = x_t[(size_t)row * 3 + d];
    if (d == 0) h0s[r][259] = 0.f;
    __syncthreads();

    // GEMV1: 259 inputs; quarter r covers [r*64, r*64+64), r==3 adds 256..258
    {
      float a0 = 0.f, a1 = 0.f, a2 = 0.f, a3 = 0.f;
      int j0 = r * 64;
      for (int jj = 0; jj < 64; jj += 4) {
        int j = j0 + jj;
        float w0 = nW1[(j + 0) * DM + d], w1 = nW1[(j + 1) * DM + d];
        float w2 = nW1[(j + 2) * DM + d], w3 = nW1[(j + 3) * DM + d];
        float4 f0 = *(const float4*)&h0s[0][j];
        float4 f1 = *(const float4*)&h0s[1][j];
        float4 f2 = *(const float4*)&h0s[2][j];
        float4 f3 = *(const float4*)&h0s[3][j];
        a0 = fmaf(f0.x, w0, fmaf(f0.y, w1, fmaf(f0.z, w2, fmaf(f0.w, w3, a0))));
        a1 = fmaf(f1.x, w0, fmaf(f1.y, w1, fmaf(f1.z, w2, fmaf(f1.w, w3, a1))));
        a2 = fmaf(f2.x, w0, fmaf(f2.y, w1, fmaf(f2.z, w2, fmaf(f2.w, w3, a2))));
        a3 = fmaf(f3.x, w0, fmaf(f3.y, w1, fmaf(f3.z, w2, fmaf(f3.w, w3, a3))));
      }
      if (r == 3) {
        for (int j = 256; j < 259; ++j) {
          float wv = nW1[j * DM + d];
          a0 = fmaf(h0s[0][j], wv, a0);
          a1 = fmaf(h0s[1][j], wv, a1);
          a2 = fmaf(h0s[2][j], wv, a2);
          a3 = fmaf(h0s[3][j], wv, a3);
        }
      }
      part[r][0][d] = a0; part[r][1][d] = a1; part[r][2][d] = a2; part[r][3][d] = a3;
    }
    __syncthreads();
    // parallel combine: quarter r finalizes row r
    float acc1v = nb1[d] + part[0][r][d] + part[1][r][d] + part[2][r][d] +
                  part[3][r][d];
    // LN1 (per-row over d)
    {
      float s1 = waveSum(acc1v), sq = waveSum(acc1v * acc1v);
      if (lane == 0) { sred1[w] = s1; sred2[w] = sq; }
      __syncthreads();
      float sx = sred1[r * 2] + sred1[r * 2 + 1];
      float sqq = sred2[r * 2] + sred2[r * 2 + 1];
      float m = sx * (1.0f / 128.0f);
      float var = sqq * (1.0f / 128.0f) - m * m;
      float y = (acc1v - m) * rsqrtf(var + EPSLN) * ng1[d] + nbe1[d];
      zz[r][d] = fmaxf(y, 0.f);
    }
    __syncthreads();
    // GEMV2: quarter covers 32 of 128
    {
      float a0 = 0.f, a1 = 0.f, a2 = 0.f, a3 = 0.f;
      int j0 = r * 32;
      for (int jj = 0; jj < 32; jj += 4) {
        int j = j0 + jj;
        float w0 = nW2[(j + 0) * DM + d], w1 = nW2[(j + 1) * DM + d];
        float w2 = nW2[(j + 2) * DM + d], w3 = nW2[(j + 3) * DM + d];
        float4 f0 = *(const float4*)&zz[0][j];
        float4 f1 = *(const float4*)&zz[1][j];
        float4 f2 = *(const float4*)&zz[2][j];
        float4 f3 = *(const float4*)&zz[3][j];
        a0 = fmaf(f0.x, w0, fmaf(f0.y, w1, fmaf(f0.z, w2, fmaf(f0.w, w3, a0))));
        a1 = fmaf(f1.x, w0, fmaf(f1.y, w1, fmaf(f1.z, w2, fmaf(f1.w, w3, a1))));
        a2 = fmaf(f2.x, w0, fmaf(f2.y, w1, fmaf(f2.z, w2, fmaf(f2.w, w3, a2))));
        a3 = fmaf(f3.x, w0, fmaf(f3.y, w1, fmaf(f3.z, w2, fmaf(f3.w, w3, a3))));
      }
      part[r][0][d] = a0; part[r][1][d] = a1; part[r][2][d] = a2; part[r][3][d] = a3;
    }
    __syncthreads();
    // parallel combine: quarter r finalizes row r
    float acc2v = nb2[d] + part[0][r][d] + part[1][r][d] + part[2][r][d] +
                  part[3][r][d];
    // LN2 + 128->3 projection
    {
      float s1 = waveSum(acc2v), sq = waveSum(acc2v * acc2v);
      if (lane == 0) { sred1[w] = s1; sred2[w] = sq; }
      __syncthreads();
      float sx = sred1[r * 2] + sred1[r * 2 + 1];
      float sqq = sred2[r * 2] + sred2[r * 2 + 1];
      float m = sx * (1.0f / 128.0f);
      float var = sqq * (1.0f / 128.0f) - m * m;
      float y = (acc2v - m) * rsqrtf(var + EPSLN) * ng2[d] + nbe2[d];
      float y2 = fmaxf(y, 0.f);
      float p0 = waveSum(y2 * nW3[d * 3 + 0]);
      float p1 = waveSum(y2 * nW3[d * 3 + 1]);
      float p2 = waveSum(y2 * nW3[d * 3 + 2]);
      if (lane == 0) { souts[w][0] = p0; souts[w][1] = p1; souts[w][2] = p2; }
    }
    __syncthreads();
    if (u < 3)
      out[(size_t)row * 3 + u] =
          souts[r * 2][u] + souts[r * 2 + 1][u] + nb3[u];
  }
}

// ---------- launch ----------
extern "C" void kernel_launch(void* const* d_in, const int* in_sizes, int n_in,
                              void* d_out, int out_size, void* d_ws,
                              size_t ws_size, hipStream_t stream) {
  const float* xyz = (const float*)d_in[0];
  const float* feat = (const float*)d_in[1];
  const float* x_t = (const float*)d_in[2];
  const int* t = (const int*)d_in[3];
  const float* Wq = (const float*)d_in[4];
  const float* bq = (const float*)d_in[5];
  const float* Wk = (const float*)d_in[6];
  const float* bk = (const float*)d_in[7];
  const float* Wv = (const float*)d_in[8];
  const float* bv = (const float*)d_in[9];
  const float* Wp1 = (const float*)d_in[10];
  const float* bp1 = (const float*)d_in[11];
  const float* Wp2 = (const float*)d_in[12];
  const float* bp2 = (const float*)d_in[13];
  const float* gamma = (const float*)d_in[14];
  const float* Wproj = (const float*)d_in[15];
  const float* bproj = (const float*)d_in[16];
  const float* tW1 = (const float*)d_in[17];
  const float* tb1 = (const float*)d_in[18];
  const float* tW2 = (const float*)d_in[19];
  const float* tb2 = (const float*)d_in[20];
  const float* nW1 = (const float*)d_in[21];
  const float* nb1 = (const float*)d_in[22];
  const float* ng1 = (const float*)d_in[23];
  const float* nbe1 = (const float*)d_in[24];
  const float* nW2 = (const float*)d_in[25];
  const float* nb2 = (const float*)d_in[26];
  const float* ng2 = (const float*)d_in[27];
  const float* nbe2 = (const float*)d_in[28];
  const float* nW3 = (const float*)d_in[29];
  const float* nb3 = (const float*)d_in[30];
  float* out = (float*)d_out;

  char* ws = (char*)d_ws;
  size_t off = 0;
  int* w_idx = (int*)(ws + off); off += (size_t)ROWS * KNN * 4;
  float* w_VfA = (float*)(ws + off); off += (size_t)ROWS * DM * 4;
  float* w_VfB = (float*)(ws + off); off += (size_t)ROWS * DM * 4;
  float* w_qsA = (float*)(ws + off); off += (size_t)ROWS * 4;
  float* w_ksA = (float*)(ws + off); off += (size_t)ROWS * 4;
  float* w_qsB = (float*)(ws + off); off += (size_t)ROWS * 4;
  float* w_ksB = (float*)(ws + off); off += (size_t)ROWS * 4;
  float* w_fA = (float*)(ws + off); off += (size_t)ROWS * DM * 4;
  float* w_fB = (float*)(ws + off); off += (size_t)ROWS * DM * 4;
  float* w_temb = (float*)(ws + off); off += (size_t)B_SZ * DM * 4;
  float* w_rs = (float*)(ws + off); off += (size_t)NLAYER * 3 * DM * 4;
  float* w_ssum = (float*)(ws + off); off += (size_t)NLAYER * 4 * 4;

  knn_kernel<<<ROWS, 256, 0, stream>>>(xyz, w_idx);
  prep_kernel<<<NLAYER + B_SZ, 128, 0, stream>>>(Wq, bq, Wk, bk, Wp2, bp2,
                                                 w_rs, w_ssum, t, tW1, tb1,
                                                 tW2, tb2, w_temb);
  vqk_kernel<<<ROWS / RBV, 256, 0, stream>>>(feat, Wv, bv, w_rs, w_ssum,
                                             w_VfA, w_qsA, w_ksA);

  const float* fins[4] = {feat, w_fA, w_fB, w_fA};
  float* fouts[4] = {w_fA, w_fB, w_fA, w_fB};
  const float* VfIn[4] = {w_VfA, w_VfB, w_VfA, w_VfB};
  float* VfOut[4] = {w_VfB, w_VfA, w_VfB, w_VfA};
  const float* qsIn[4] = {w_qsA, w_qsB, w_qsA, w_qsB};
  float* qsOut[4] = {w_qsB, w_qsA, w_qsB, w_qsA};
  const float* ksIn[4] = {w_ksA, w_ksB, w_ksA, w_ksB};
  float* ksOut[4] = {w_ksB, w_ksA, w_ksB, w_ksA};

  for (int l = 0; l < NLAYER; ++l) {
    const float* rsL = w_rs + (size_t)l * 3 * DM;
    const float* ssL = w_ssum + (size_t)l * 4;
    int ln = (l + 1 < NLAYER) ? (l + 1) : l;
    const float* rsN = w_rs + (size_t)ln * 3 * DM;
    const float* ssN = w_ssum + (size_t)ln * 4;
    if (l < NLAYER - 1) {
      fused_layer_kernel<0><<<ROWS / 4, 512, 0, stream>>>(
          xyz, w_idx, fins[l], VfIn[l], qsIn[l], ksIn[l],
          Wp1 + (size_t)l * 3 * DM, bp1 + (size_t)l * DM, rsL, ssL,
          Wp2 + (size_t)l * DM * DM, bp2 + (size_t)l * DM,
          Wproj + (size_t)l * DM * DM, bproj + (size_t)l * DM, gamma, l,
          fouts[l], Wv + (size_t)ln * DM * DM, bv + (size_t)ln * DM, rsN, ssN,
          VfOut[l], qsOut[l], ksOut[l], x_t, w_temb, nW1, nb1, ng1, nbe1, nW2,
          nb2, ng2, nbe2, nW3, nb3, out);
    } else {
      fused_layer_kernel<1><<<ROWS / 4, 512, 0, stream>>>(
          xyz, w_idx, fins[l], VfIn[l], qsIn[l], ksIn[l],
          Wp1 + (size_t)l * 3 * DM, bp1 + (size_t)l * DM, rsL, ssL,
          Wp2 + (size_t)l * DM * DM, bp2 + (size_t)l * DM,
          Wproj + (size_t)l * DM * DM, bproj + (size_t)l * DM, gamma, l,
          fouts[l], Wv + (size_t)ln * DM * DM, bv + (size_t)ln * DM, rsN, ssN,
          VfOut[l], qsOut[l], ksOut[l], x_t, w_temb, nW1, nb1, ng1, nbe1, nW2,
          nb2, ng2, nbe2, nW3, nb3, out);
    }
  }
}

// Round 9
// 194.681 us; speedup vs baseline: 1.1788x; 1.0917x over previous
//
#include <hip/hip_runtime.h>
#include <math.h>

#define B_SZ 2
#define N_PTS 2048
#define DM 128
#define KNN 128
#define NLAYER 4
#define ROWS (B_SZ * N_PTS)
#define RBV 4
#define RB8 8
#define EPSLN 1e-5f

// ---------- reductions ----------
__device__ __forceinline__ float waveSum(float v) {
#pragma unroll
  for (int o = 32; o > 0; o >>= 1) v += __shfl_xor(v, o, 64);
  return v;
}
__device__ __forceinline__ float waveMax(float v) {
#pragma unroll
  for (int o = 32; o > 0; o >>= 1) v = fmaxf(v, __shfl_xor(v, o, 64));
  return v;
}
__device__ __forceinline__ float blockSum128(float v, float* s2, int t) {
  float w = waveSum(v);
  __syncthreads();
  if ((t & 63) == 0) s2[t >> 6] = w;
  __syncthreads();
  return s2[0] + s2[1];
}
__device__ __forceinline__ unsigned waveScanIncl(unsigned v, int lane) {
#pragma unroll
  for (int o = 1; o < 64; o <<= 1) {
    unsigned u = (unsigned)__shfl_up((int)v, o, 64);
    if (lane >= o) v += u;
  }
  return v;
}

// 8-row GEMV partial: a[8] accumulators, src has row stride STRIDE floats
template <int STRIDE>
__device__ __forceinline__ void gemv8(const float* src, const float* W, int j0,
                                      int cnt, int d, float* a) {
  for (int jj = 0; jj < cnt; jj += 4) {
    int j = j0 + jj;
    float w0 = W[(j + 0) * DM + d], w1 = W[(j + 1) * DM + d];
    float w2 = W[(j + 2) * DM + d], w3 = W[(j + 3) * DM + d];
#pragma unroll
    for (int rr = 0; rr < 8; ++rr) {
      float4 f = *(const float4*)(src + rr * STRIDE + j);
      a[rr] = fmaf(f.x, w0, fmaf(f.y, w1, fmaf(f.z, w2, fmaf(f.w, w3, a[rr]))));
    }
  }
}

// ---------- 1. knn ----------
__global__ __launch_bounds__(256) void knn_kernel(const float* __restrict__ xyz,
                                                  int* __restrict__ idx) {
  int row = blockIdx.x;
  int b = row >> 11, i = row & (N_PTS - 1);
  const float* xb = xyz + (size_t)b * N_PTS * 3;
  int tid = threadIdx.x;
  int lane = tid & 63, wid = tid >> 6;

  __shared__ unsigned hist[256];
  __shared__ unsigned wred[4];
  __shared__ unsigned sel[2];

  float xi = xb[i * 3 + 0], yi = xb[i * 3 + 1], zi = xb[i * 3 + 2];
  float sqi = xi * xi + yi * yi + zi * zi;

  float p[24];
  {
    const float4* xb4 = (const float4*)xb;
#pragma unroll
    for (int q = 0; q < 6; ++q) {
      float4 v = xb4[tid * 6 + q];
      p[q * 4 + 0] = v.x; p[q * 4 + 1] = v.y; p[q * 4 + 2] = v.z; p[q * 4 + 3] = v.w;
    }
  }
  unsigned key[8];
#pragma unroll
  for (int s = 0; s < 8; ++s) {
    float xj = p[s * 3 + 0], yj = p[s * 3 + 1], zj = p[s * 3 + 2];
    float d = sqi + xj * xj + yj * yj + zj * zj -
              2.0f * (xi * xj + yi * yj + zi * zj);
    unsigned u = __float_as_uint(d);
    key[s] = (u & 0x80000000u) ? ~u : (u | 0x80000000u);
  }

  unsigned prefix = 0;
  unsigned need = KNN;
  for (int shift = 24; shift >= 0; shift -= 8) {
    hist[tid] = 0;
    __syncthreads();
    if (shift == 24) {
#pragma unroll
      for (int s = 0; s < 8; ++s) {
        unsigned bin = key[s] >> 24;
        unsigned long long act = __ballot(1);
        while (act) {
          int src = __builtin_ctzll(act);
          unsigned bsel = (unsigned)__shfl((int)bin, src, 64);
          unsigned long long grp = __ballot(bin == bsel);
          if (lane == src)
            atomicAdd(&hist[bsel], (unsigned)__builtin_popcountll(grp));
          act &= ~grp;
        }
      }
    } else {
#pragma unroll
      for (int s = 0; s < 8; ++s) {
        unsigned k = key[s];
        if ((k >> (shift + 8)) == prefix)
          atomicAdd(&hist[(k >> shift) & 255u], 1u);
      }
    }
    __syncthreads();
    unsigned h = hist[tid];
    unsigned incl = waveScanIncl(h, lane);
    if (lane == 63) wred[wid] = incl;
    __syncthreads();
    unsigned offs = 0;
    for (int w = 0; w < wid; ++w) offs += wred[w];
    incl += offs;
    unsigned excl = incl - h;
    if (excl < need && need <= incl) { sel[0] = (unsigned)tid; sel[1] = need - excl; }
    __syncthreads();
    prefix = (prefix << 8) | sel[0];
    need = sel[1];
  }
  unsigned T = prefix;
  int need_eq = (int)need;

  unsigned clt = 0, ceq = 0;
#pragma unroll
  for (int s = 0; s < 8; ++s) {
    clt += (key[s] < T);
    ceq += (key[s] == T);
  }
  unsigned packed = clt | (ceq << 16);
  unsigned incl = waveScanIncl(packed, lane);
  if (lane == 63) wred[wid] = incl;
  __syncthreads();
  unsigned offs = 0;
  for (int w = 0; w < wid; ++w) offs += wred[w];
  unsigned totAll = wred[0] + wred[1] + wred[2] + wred[3];
  incl += offs;
  unsigned excl = incl - packed;
  int lt_base = (int)(excl & 0xFFFFu);
  int eq_base = (int)(excl >> 16);
  int total_lt = (int)(totAll & 0xFFFFu);

  int* orow = idx + (size_t)row * KNN;
  int lpos = 0, epos = 0;
#pragma unroll
  for (int s = 0; s < 8; ++s) {
    int j = tid * 8 + s;
    unsigned k = key[s];
    if (k < T) {
      orow[lt_base + lpos] = j; lpos++;
    } else if (k == T) {
      int r = eq_base + epos; epos++;
      if (r < need_eq) orow[total_lt + r] = j;
    }
  }
}

// ---------- 2. prep: rowsums + temb ----------
__global__ __launch_bounds__(128) void prep_kernel(
    const float* __restrict__ Wq, const float* __restrict__ bq,
    const float* __restrict__ Wk, const float* __restrict__ bk,
    const float* __restrict__ Wp2, const float* __restrict__ bp2,
    float* __restrict__ rs, float* __restrict__ ssum,
    const int* __restrict__ t, const float* __restrict__ tW1,
    const float* __restrict__ tb1, const float* __restrict__ tW2,
    const float* __restrict__ tb2, float* __restrict__ temb) {
  int blk = blockIdx.x, d = threadIdx.x;
  __shared__ float s2[2];
  __shared__ float emb[DM];
  __shared__ float h1[DM];
  if (blk < NLAYER) {
    int l = blk;
    const float* wq = Wq + (size_t)l * DM * DM;
    const float* wk = Wk + (size_t)l * DM * DM;
    const float* wp2 = Wp2 + (size_t)l * DM * DM;
    float a = 0.f, b = 0.f, c = 0.f;
    for (int j = 0; j < DM; ++j) {
      a += wq[d * DM + j];
      b += wk[d * DM + j];
      c += wp2[d * DM + j];
    }
    rs[l * 3 * DM + d] = a;
    rs[l * 3 * DM + DM + d] = b;
    rs[l * 3 * DM + 2 * DM + d] = c;
    float sq = blockSum128(bq[l * DM + d], s2, d);
    float sk = blockSum128(bk[l * DM + d], s2, d);
    float sp = blockSum128(bp2[l * DM + d], s2, d);
    if (d == 0) { ssum[l * 4 + 0] = sq; ssum[l * 4 + 1] = sk; ssum[l * 4 + 2] = sp; }
  } else {
    int b = blk - NLAYER;
    float tv = (float)t[b];
    float lg = logf(10000.0f);
    if (d < 64) {
      float f = expf(-lg * (float)d / 63.0f);
      emb[d] = sinf(tv * f);
    } else {
      float f = expf(-lg * (float)(d - 64) / 63.0f);
      emb[d] = cosf(tv * f);
    }
    __syncthreads();
    float acc = tb1[d];
    for (int j = 0; j < DM; ++j) acc = fmaf(emb[j], tW1[j * DM + d], acc);
    h1[d] = fmaxf(acc, 0.f);
    __syncthreads();
    float acc2 = tb2[d];
    for (int j = 0; j < DM; ++j) acc2 = fmaf(h1[j], tW2[j * DM + d], acc2);
    temb[b * DM + d] = acc2;
  }
}

// ---------- 3. V projection + q/k sums for layer 0 ----------
__global__ __launch_bounds__(256) void vqk_kernel(
    const float* __restrict__ feat, const float* __restrict__ Wv,
    const float* __restrict__ bv, const float* __restrict__ rs,
    const float* __restrict__ ssum, float* __restrict__ Vf,
    float* __restrict__ qsum, float* __restrict__ ksum) {
  int n0 = blockIdx.x * RBV;
  int t = threadIdx.x;
  int d = t & 127, half = t >> 7;
  __shared__ float fr[RBV][DM];
  __shared__ float part[RBV][DM];
  __shared__ float sA[2][RBV];
  __shared__ float sB[2][RBV];
#pragma unroll
  for (int u = 0; u < 2; ++u) {
    int r = half * 2 + u;
    fr[r][d] = feat[(size_t)(n0 + r) * DM + d];
  }
  __syncthreads();
  float acc[RBV] = {0.f, 0.f, 0.f, 0.f};
  int j0 = half * 64;
  for (int jj = 0; jj < 64; jj += 4) {
    int j = j0 + jj;
    float w0 = Wv[(j + 0) * DM + d], w1 = Wv[(j + 1) * DM + d];
    float w2 = Wv[(j + 2) * DM + d], w3 = Wv[(j + 3) * DM + d];
#pragma unroll
    for (int r = 0; r < RBV; ++r) {
      float4 f = *(const float4*)&fr[r][j];
      acc[r] = fmaf(f.x, w0, fmaf(f.y, w1, fmaf(f.z, w2, fmaf(f.w, w3, acc[r]))));
    }
  }
  if (half == 1) {
#pragma unroll
    for (int r = 0; r < RBV; ++r) part[r][d] = acc[r];
  }
  __syncthreads();
  if (half == 0) {
    float bvd = bv[d];
#pragma unroll
    for (int r = 0; r < RBV; ++r)
      Vf[(size_t)(n0 + r) * DM + d] = acc[r] + part[r][d] + bvd;
    int lane = t & 63, wid = (t >> 6) & 1;
    float rsq = rs[d], rsk = rs[DM + d];
#pragma unroll
    for (int r = 0; r < RBV; ++r) {
      float f = fr[r][d];
      float a = waveSum(f * rsq);
      float k = waveSum(f * rsk);
      if (lane == 0) { sA[wid][r] = a; sB[wid][r] = k; }
    }
  }
  __syncthreads();
  if (t < RBV) qsum[n0 + t] = sA[0][t] + sA[1][t] + ssum[0];
  if (t >= 64 && t < 64 + RBV) {
    int r = t - 64;
    ksum[n0 + r] = sB[0][r] + sB[1][r] + ssum[1];
  }
}

// ---------- 4. fused layer: 512 threads, 8 rows/block, wave-per-row A/B ----------
template <int LAST>
__global__ __launch_bounds__(512, 4) void fused_layer_kernel(
    const float* __restrict__ xyz, const int* __restrict__ idx,
    const float* __restrict__ fin, const float* __restrict__ Vf_in,
    const float* __restrict__ qsum_in, const float* __restrict__ ksum_in,
    const float* __restrict__ Wp1, const float* __restrict__ bp1,
    const float* __restrict__ rsL, const float* __restrict__ ssL,
    const float* __restrict__ Wp2, const float* __restrict__ bp2,
    const float* __restrict__ Wproj, const float* __restrict__ bproj,
    const float* __restrict__ gamma, int l, float* __restrict__ fout,
    const float* __restrict__ Wv_n, const float* __restrict__ bv_n,
    const float* __restrict__ rs_n, const float* __restrict__ ss_n,
    float* __restrict__ Vf_out, float* __restrict__ qsum_out,
    float* __restrict__ ksum_out,
    const float* __restrict__ x_t, const float* __restrict__ temb,
    const float* __restrict__ nW1, const float* __restrict__ nb1,
    const float* __restrict__ ng1, const float* __restrict__ nbe1,
    const float* __restrict__ nW2, const float* __restrict__ nb2,
    const float* __restrict__ ng2, const float* __restrict__ nbe2,
    const float* __restrict__ nW3, const float* __restrict__ nb3,
    float* __restrict__ out) {
  int n0 = blockIdx.x * RB8;
  int t = threadIdx.x;
  int w = t >> 6, lane = t & 63;
  int q = t >> 7, d = t & 127;
  int b = n0 >> 11;

  __shared__ float4 rel4[RB8][KNN];   // 16 KB; overlaid by part[4][8][128] after B
  __shared__ int joff[RB8][KNN];      // 4 KB
  __shared__ float hrow[RB8][DM];     // hagg -> fo
  __shared__ float zz[RB8][DM];       // vagg -> z -> LN buffers
  float* part = (float*)rel4;         // [4][8][128]

  const float* xb = xyz + (size_t)b * N_PTS * 3;

  // ---- Phase A (barrier-free): wave w owns row n0+w; lane -> k=lane, lane+64
  {
    int row = n0 + w;
    int i = row & (N_PTS - 1);
    float xi = xb[i * 3 + 0], yi = xb[i * 3 + 1], zi = xb[i * 3 + 2];
    int j1 = idx[(size_t)row * KNN + lane];
    int j2 = idx[(size_t)row * KNN + lane + 64];
    float rx1 = xi - xb[j1 * 3 + 0], ry1 = yi - xb[j1 * 3 + 1], rz1 = zi - xb[j1 * 3 + 2];
    float rx2 = xi - xb[j2 * 3 + 0], ry2 = yi - xb[j2 * 3 + 1], rz2 = zi - xb[j2 * 3 + 2];

    const float4* W1x = (const float4*)Wp1;
    const float4* W1y = (const float4*)(Wp1 + DM);
    const float4* W1z = (const float4*)(Wp1 + 2 * DM);
    const float4* Bp = (const float4*)bp1;
    const float4* W2 = (const float4*)(rsL + 2 * DM);
    float acc1 = 0.f, acc2 = 0.f;
#pragma unroll 8
    for (int qq = 0; qq < DM / 4; ++qq) {
      float4 ax = W1x[qq], ay = W1y[qq], az = W1z[qq], ab = Bp[qq], c = W2[qq];
      float hA = fmaxf(fmaf(rx1, ax.x, fmaf(ry1, ay.x, fmaf(rz1, az.x, ab.x))), 0.f);
      float hB = fmaxf(fmaf(rx1, ax.y, fmaf(ry1, ay.y, fmaf(rz1, az.y, ab.y))), 0.f);
      float hC = fmaxf(fmaf(rx1, ax.z, fmaf(ry1, ay.z, fmaf(rz1, az.z, ab.z))), 0.f);
      float hD = fmaxf(fmaf(rx1, ax.w, fmaf(ry1, ay.w, fmaf(rz1, az.w, ab.w))), 0.f);
      acc1 = fmaf(hA, c.x, fmaf(hB, c.y, fmaf(hC, c.z, fmaf(hD, c.w, acc1))));
      float hE = fmaxf(fmaf(rx2, ax.x, fmaf(ry2, ay.x, fmaf(rz2, az.x, ab.x))), 0.f);
      float hF = fmaxf(fmaf(rx2, ax.y, fmaf(ry2, ay.y, fmaf(rz2, az.y, ab.y))), 0.f);
      float hG = fmaxf(fmaf(rx2, ax.z, fmaf(ry2, ay.z, fmaf(rz2, az.z, ab.z))), 0.f);
      float hH = fmaxf(fmaf(rx2, ax.w, fmaf(ry2, ay.w, fmaf(rz2, az.w, ab.w))), 0.f);
      acc2 = fmaf(hE, c.x, fmaf(hF, c.y, fmaf(hG, c.z, fmaf(hH, c.w, acc2))));
    }
    float qs = qsum_in[row] + ssL[2];
    float l1 = qs - ksum_in[b * N_PTS + j1] + acc1;
    float l2 = qs - ksum_in[b * N_PTS + j2] + acc2;
    float m = waveMax(fmaxf(l1, l2));
    float e1 = __expf(l1 - m), e2 = __expf(l2 - m);
    float s = waveSum(e1 + e2);
    float inv = 1.0f / s;
    rel4[w][lane] = make_float4(rx1, ry1, rz1, e1 * inv);
    rel4[w][lane + 64] = make_float4(rx2, ry2, rz2, e2 * inv);
    joff[w][lane] = j1 * (DM * 4);
    joff[w][lane + 64] = j2 * (DM * 4);
  }
  __syncthreads();

  // ---- Phase B (barrier-free): wave w owns row n0+w; lane -> d=lane, lane+64
  {
    int d1 = lane, d2 = lane + 64;
    float wx1 = Wp1[d1], wy1 = Wp1[DM + d1], wz1 = Wp1[2 * DM + d1], wb1 = bp1[d1];
    float wx2 = Wp1[d2], wy2 = Wp1[DM + d2], wz2 = Wp1[2 * DM + d2], wb2 = bp1[d2];
    const char* vbase = (const char*)(Vf_in + (size_t)b * N_PTS * DM);
    const char* v1 = vbase + (size_t)d1 * 4;
    const char* v2 = vbase + (size_t)d2 * 4;
    float ha1a = 0.f, ha1b = 0.f, ha2a = 0.f, ha2b = 0.f;
    float va1a = 0.f, va1b = 0.f, va2a = 0.f, va2b = 0.f;
#pragma unroll 4
    for (int k = 0; k < KNN; k += 2) {
      float4 ra = rel4[w][k];
      float4 rb = rel4[w][k + 1];
      int ja = joff[w][k], jb = joff[w][k + 1];
      float Va1 = *(const float*)(v1 + ja);
      float Vb1 = *(const float*)(v1 + jb);
      float Va2 = *(const float*)(v2 + ja);
      float Vb2 = *(const float*)(v2 + jb);
      float hA1 = fmaxf(fmaf(ra.x, wx1, fmaf(ra.y, wy1, fmaf(ra.z, wz1, wb1))), 0.f);
      float hB1 = fmaxf(fmaf(rb.x, wx1, fmaf(rb.y, wy1, fmaf(rb.z, wz1, wb1))), 0.f);
      float hA2 = fmaxf(fmaf(ra.x, wx2, fmaf(ra.y, wy2, fmaf(ra.z, wz2, wb2))), 0.f);
      float hB2 = fmaxf(fmaf(rb.x, wx2, fmaf(rb.y, wy2, fmaf(rb.z, wz2, wb2))), 0.f);
      ha1a = fmaf(ra.w, hA1, ha1a);
      ha1b = fmaf(rb.w, hB1, ha1b);
      ha2a = fmaf(ra.w, hA2, ha2a);
      ha2b = fmaf(rb.w, hB2, ha2b);
      va1a = fmaf(ra.w, Va1, va1a);
      va1b = fmaf(rb.w, Vb1, va1b);
      va2a = fmaf(ra.w, Va2, va2a);
      va2b = fmaf(rb.w, Vb2, va2b);
    }
    hrow[w][d1] = ha1a + ha1b;
    hrow[w][d2] = ha2a + ha2b;
    zz[w][d1] = va1a + va1b;
    zz[w][d2] = va2a + va2b;
  }
  __syncthreads();

  // ---- Phase C1: z = vagg + hagg@Wp2 + bp2  (quarter-split, 8-row batch)
  {
    float a[RB8] = {0.f, 0.f, 0.f, 0.f, 0.f, 0.f, 0.f, 0.f};
    gemv8<DM>(&hrow[0][0], Wp2, q * 32, 32, d, a);
    float* pq = part + (q * RB8) * DM + d;
#pragma unroll
    for (int rr = 0; rr < RB8; ++rr) pq[rr * DM] = a[rr];
  }
  __syncthreads();
  {
    int r0 = q * 2, r1 = q * 2 + 1;
    float bpd = bp2[d];
    zz[r0][d] += part[(0 * RB8 + r0) * DM + d] + part[(1 * RB8 + r0) * DM + d] +
                 part[(2 * RB8 + r0) * DM + d] + part[(3 * RB8 + r0) * DM + d] + bpd;
    zz[r1][d] += part[(0 * RB8 + r1) * DM + d] + part[(1 * RB8 + r1) * DM + d] +
                 part[(2 * RB8 + r1) * DM + d] + part[(3 * RB8 + r1) * DM + d] + bpd;
  }
  __syncthreads();

  // ---- Phase C2: fo = fin + gamma*(z@Wproj + bproj)
  {
    float a[RB8] = {0.f, 0.f, 0.f, 0.f, 0.f, 0.f, 0.f, 0.f};
    gemv8<DM>(&zz[0][0], Wproj, q * 32, 32, d, a);
    float* pq = part + (q * RB8) * DM + d;
#pragma unroll
    for (int rr = 0; rr < RB8; ++rr) pq[rr * DM] = a[rr];
  }
  __syncthreads();
  {
    int r0 = q * 2, r1 = q * 2 + 1;
    float g = gamma[l];
    float bpr = bproj[d];
    float s0 = part[(0 * RB8 + r0) * DM + d] + part[(1 * RB8 + r0) * DM + d] +
               part[(2 * RB8 + r0) * DM + d] + part[(3 * RB8 + r0) * DM + d] + bpr;
    float s1 = part[(0 * RB8 + r1) * DM + d] + part[(1 * RB8 + r1) * DM + d] +
               part[(2 * RB8 + r1) * DM + d] + part[(3 * RB8 + r1) * DM + d] + bpr;
    float fo0 = fin[(size_t)(n0 + r0) * DM + d] + g * s0;
    float fo1 = fin[(size_t)(n0 + r1) * DM + d] + g * s1;
    if (!LAST) {
      fout[(size_t)(n0 + r0) * DM + d] = fo0;
      fout[(size_t)(n0 + r1) * DM + d] = fo1;
    }
    hrow[r0][d] = fo0;
    hrow[r1][d] = fo1;
  }
  __syncthreads();

  if constexpr (!LAST) {
    // ---- Phase D: q/k sums (wave-per-row) + next layer's V projection
    {
      int d1 = lane, d2 = lane + 64;
      float fo1 = hrow[w][d1], fo2 = hrow[w][d2];
      float qp = waveSum(fo1 * rs_n[d1] + fo2 * rs_n[d2]);
      float kp = waveSum(fo1 * rs_n[DM + d1] + fo2 * rs_n[DM + d2]);
      if (lane == 0) {
        qsum_out[n0 + w] = qp + ss_n[0];
        ksum_out[n0 + w] = kp + ss_n[1];
      }
    }
    {
      float a[RB8] = {0.f, 0.f, 0.f, 0.f, 0.f, 0.f, 0.f, 0.f};
      gemv8<DM>(&hrow[0][0], Wv_n, q * 32, 32, d, a);
      float* pq = part + (q * RB8) * DM + d;
#pragma unroll
      for (int rr = 0; rr < RB8; ++rr) pq[rr * DM] = a[rr];
    }
    __syncthreads();
    {
      int r0 = q * 2, r1 = q * 2 + 1;
      float bvd = bv_n[d];
      Vf_out[(size_t)(n0 + r0) * DM + d] =
          part[(0 * RB8 + r0) * DM + d] + part[(1 * RB8 + r0) * DM + d] +
          part[(2 * RB8 + r0) * DM + d] + part[(3 * RB8 + r0) * DM + d] + bvd;
      Vf_out[(size_t)(n0 + r1) * DM + d] =
          part[(0 * RB8 + r1) * DM + d] + part[(1 * RB8 + r1) * DM + d] +
          part[(2 * RB8 + r1) * DM + d] + part[(3 * RB8 + r1) * DM + d] + bvd;
    }
  } else {
    // ---- Head: concat -> GEMV1 -> LN1 -> GEMV2 -> LN2 -> out proj
    __shared__ float h0s[RB8][260];
    {
      int r0 = q * 2, r1 = q * 2 + 1;
#pragma unroll
      for (int rr = r0; rr <= r1; ++rr) {
        h0s[rr][3 + d] = hrow[rr][d];
        h0s[rr][131 + d] = temb[b * DM + d];
        if (d < 3) h0s[rr][d] = x_t[(size_t)(n0 + rr) * 3 + d];
        if (d == 0) h0s[rr][259] = 0.f;
      }
    }
    __syncthreads();

    // GEMV1: 259 inputs; quarter q covers [q*64, q*64+64), q==3 adds 256..258
    {
      float a[RB8] = {0.f, 0.f, 0.f, 0.f, 0.f, 0.f, 0.f, 0.f};
      gemv8<260>(&h0s[0][0], nW1, q * 64, 64, d, a);
      if (q == 3) {
        for (int j = 256; j < 259; ++j) {
          float wv = nW1[j * DM + d];
#pragma unroll
          for (int rr = 0; rr < RB8; ++rr) a[rr] = fmaf(h0s[rr][j], wv, a[rr]);
        }
      }
      float* pq = part + (q * RB8) * DM + d;
#pragma unroll
      for (int rr = 0; rr < RB8; ++rr) pq[rr * DM] = a[rr];
    }
    __syncthreads();
    {
      int r0 = q * 2, r1 = q * 2 + 1;
      float nb = nb1[d];
      zz[r0][d] = nb + part[(0 * RB8 + r0) * DM + d] + part[(1 * RB8 + r0) * DM + d] +
                  part[(2 * RB8 + r0) * DM + d] + part[(3 * RB8 + r0) * DM + d];
      zz[r1][d] = nb + part[(0 * RB8 + r1) * DM + d] + part[(1 * RB8 + r1) * DM + d] +
                  part[(2 * RB8 + r1) * DM + d] + part[(3 * RB8 + r1) * DM + d];
    }
    __syncthreads();
    // LN1 per wave (row w)
    {
      int d1 = lane, d2 = lane + 64;
      float x1 = zz[w][d1], x2 = zz[w][d2];
      float s1 = waveSum(x1 + x2);
      float sq = waveSum(x1 * x1 + x2 * x2);
      float m = s1 * (1.0f / 128.0f);
      float var = sq * (1.0f / 128.0f) - m * m;
      float rstd = rsqrtf(var + EPSLN);
      float y1 = fmaxf((x1 - m) * rstd * ng1[d1] + nbe1[d1], 0.f);
      float y2 = fmaxf((x2 - m) * rstd * ng1[d2] + nbe1[d2], 0.f);
      zz[w][d1] = y1;
      zz[w][d2] = y2;
    }
    __syncthreads();
    // GEMV2: quarter q covers [q*32, q*32+32)
    {
      float a[RB8] = {0.f, 0.f, 0.f, 0.f, 0.f, 0.f, 0.f, 0.f};
      gemv8<DM>(&zz[0][0], nW2, q * 32, 32, d, a);
      float* pq = part + (q * RB8) * DM + d;
#pragma unroll
      for (int rr = 0; rr < RB8; ++rr) pq[rr * DM] = a[rr];
    }
    __syncthreads();
    {
      int r0 = q * 2, r1 = q * 2 + 1;
      float nb = nb2[d];
      hrow[r0][d] = nb + part[(0 * RB8 + r0) * DM + d] + part[(1 * RB8 + r0) * DM + d] +
                    part[(2 * RB8 + r0) * DM + d] + part[(3 * RB8 + r0) * DM + d];
      hrow[r1][d] = nb + part[(0 * RB8 + r1) * DM + d] + part[(1 * RB8 + r1) * DM + d] +
                    part[(2 * RB8 + r1) * DM + d] + part[(3 * RB8 + r1) * DM + d];
    }
    __syncthreads();
    // LN2 + 128->3 projection per wave (row w)
    {
      int d1 = lane, d2 = lane + 64;
      float x1 = hrow[w][d1], x2 = hrow[w][d2];
      float s1 = waveSum(x1 + x2);
      float sq = waveSum(x1 * x1 + x2 * x2);
      float m = s1 * (1.0f / 128.0f);
      float var = sq * (1.0f / 128.0f) - m * m;
      float rstd = rsqrtf(var + EPSLN);
      float y1 = fmaxf((x1 - m) * rstd * ng2[d1] + nbe2[d1], 0.f);
      float y2 = fmaxf((x2 - m) * rstd * ng2[d2] + nbe2[d2], 0.f);
      float p0 = waveSum(y1 * nW3[d1 * 3 + 0] + y2 * nW3[d2 * 3 + 0]);
      float p1 = waveSum(y1 * nW3[d1 * 3 + 1] + y2 * nW3[d2 * 3 + 1]);
      float p2 = waveSum(y1 * nW3[d1 * 3 + 2] + y2 * nW3[d2 * 3 + 2]);
      if (lane == 0) {
        out[(size_t)(n0 + w) * 3 + 0] = p0 + nb3[0];
        out[(size_t)(n0 + w) * 3 + 1] = p1 + nb3[1];
        out[(size_t)(n0 + w) * 3 + 2] = p2 + nb3[2];
      }
    }
  }
}

// ---------- launch ----------
extern "C" void kernel_launch(void* const* d_in, const int* in_sizes, int n_in,
                              void* d_out, int out_size, void* d_ws,
                              size_t ws_size, hipStream_t stream) {
  const float* xyz = (const float*)d_in[0];
  const float* feat = (const float*)d_in[1];
  const float* x_t = (const float*)d_in[2];
  const int* t = (const int*)d_in[3];
  const float* Wq = (const float*)d_in[4];
  const float* bq = (const float*)d_in[5];
  const float* Wk = (const float*)d_in[6];
  const float* bk = (const float*)d_in[7];
  const float* Wv = (const float*)d_in[8];
  const float* bv = (const float*)d_in[9];
  const float* Wp1 = (const float*)d_in[10];
  const float* bp1 = (const float*)d_in[11];
  const float* Wp2 = (const float*)d_in[12];
  const float* bp2 = (const float*)d_in[13];
  const float* gamma = (const float*)d_in[14];
  const float* Wproj = (const float*)d_in[15];
  const float* bproj = (const float*)d_in[16];
  const float* tW1 = (const float*)d_in[17];
  const float* tb1 = (const float*)d_in[18];
  const float* tW2 = (const float*)d_in[19];
  const float* tb2 = (const float*)d_in[20];
  const float* nW1 = (const float*)d_in[21];
  const float* nb1 = (const float*)d_in[22];
  const float* ng1 = (const float*)d_in[23];
  const float* nbe1 = (const float*)d_in[24];
  const float* nW2 = (const float*)d_in[25];
  const float* nb2 = (const float*)d_in[26];
  const float* ng2 = (const float*)d_in[27];
  const float* nbe2 = (const float*)d_in[28];
  const float* nW3 = (const float*)d_in[29];
  const float* nb3 = (const float*)d_in[30];
  float* out = (float*)d_out;

  char* ws = (char*)d_ws;
  size_t off = 0;
  int* w_idx = (int*)(ws + off); off += (size_t)ROWS * KNN * 4;
  float* w_VfA = (float*)(ws + off); off += (size_t)ROWS * DM * 4;
  float* w_VfB = (float*)(ws + off); off += (size_t)ROWS * DM * 4;
  float* w_qsA = (float*)(ws + off); off += (size_t)ROWS * 4;
  float* w_ksA = (float*)(ws + off); off += (size_t)ROWS * 4;
  float* w_qsB = (float*)(ws + off); off += (size_t)ROWS * 4;
  float* w_ksB = (float*)(ws + off); off += (size_t)ROWS * 4;
  float* w_fA = (float*)(ws + off); off += (size_t)ROWS * DM * 4;
  float* w_fB = (float*)(ws + off); off += (size_t)ROWS * DM * 4;
  float* w_temb = (float*)(ws + off); off += (size_t)B_SZ * DM * 4;
  float* w_rs = (float*)(ws + off); off += (size_t)NLAYER * 3 * DM * 4;
  float* w_ssum = (float*)(ws + off); off += (size_t)NLAYER * 4 * 4;

  knn_kernel<<<ROWS, 256, 0, stream>>>(xyz, w_idx);
  prep_kernel<<<NLAYER + B_SZ, 128, 0, stream>>>(Wq, bq, Wk, bk, Wp2, bp2,
                                                 w_rs, w_ssum, t, tW1, tb1,
                                                 tW2, tb2, w_temb);
  vqk_kernel<<<ROWS / RBV, 256, 0, stream>>>(feat, Wv, bv, w_rs, w_ssum,
                                             w_VfA, w_qsA, w_ksA);

  const float* fins[4] = {feat, w_fA, w_fB, w_fA};
  float* fouts[4] = {w_fA, w_fB, w_fA, w_fB};
  const float* VfIn[4] = {w_VfA, w_VfB, w_VfA, w_VfB};
  float* VfOut[4] = {w_VfB, w_VfA, w_VfB, w_VfA};
  const float* qsIn[4] = {w_qsA, w_qsB, w_qsA, w_qsB};
  float* qsOut[4] = {w_qsB, w_qsA, w_qsB, w_qsA};
  const float* ksIn[4] = {w_ksA, w_ksB, w_ksA, w_ksB};
  float* ksOut[4] = {w_ksB, w_ksA, w_ksB, w_ksA};

  for (int l = 0; l < NLAYER; ++l) {
    const float* rsL = w_rs + (size_t)l * 3 * DM;
    const float* ssL = w_ssum + (size_t)l * 4;
    int ln = (l + 1 < NLAYER) ? (l + 1) : l;
    const float* rsN = w_rs + (size_t)ln * 3 * DM;
    const float* ssN = w_ssum + (size_t)ln * 4;
    if (l < NLAYER - 1) {
      fused_layer_kernel<0><<<ROWS / RB8, 512, 0, stream>>>(
          xyz, w_idx, fins[l], VfIn[l], qsIn[l], ksIn[l],
          Wp1 + (size_t)l * 3 * DM, bp1 + (size_t)l * DM, rsL, ssL,
          Wp2 + (size_t)l * DM * DM, bp2 + (size_t)l * DM,
          Wproj + (size_t)l * DM * DM, bproj + (size_t)l * DM, gamma, l,
          fouts[l], Wv + (size_t)ln * DM * DM, bv + (size_t)ln * DM, rsN, ssN,
          VfOut[l], qsOut[l], ksOut[l], x_t, w_temb, nW1, nb1, ng1, nbe1, nW2,
          nb2, ng2, nbe2, nW3, nb3, out);
    } else {
      fused_layer_kernel<1><<<ROWS / RB8, 512, 0, stream>>>(
          xyz, w_idx, fins[l], VfIn[l], qsIn[l], ksIn[l],
          Wp1 + (size_t)l * 3 * DM, bp1 + (size_t)l * DM, rsL, ssL,
          Wp2 + (size_t)l * DM * DM, bp2 + (size_t)l * DM,
          Wproj + (size_t)l * DM * DM, bproj + (size_t)l * DM, gamma, l,
          fouts[l], Wv + (size_t)ln * DM * DM, bv + (size_t)ln * DM, rsN, ssN,
          VfOut[l], qsOut[l], ksOut[l], x_t, w_temb, nW1, nb1, ng1, nbe1, nW2,
          nb2, ng2, nbe2, nW3, nb3, out);
    }
  }
}

// Round 10
// 190.128 us; speedup vs baseline: 1.2071x; 1.0239x over previous
//
#include <hip/hip_runtime.h>
#include <math.h>

#define B_SZ 2
#define N_PTS 2048
#define DM 128
#define KNN 128
#define NLAYER 4
#define ROWS (B_SZ * N_PTS)
#define RBV 4
#define RB8 8
#define EPSLN 1e-5f

// ---------- reductions ----------
__device__ __forceinline__ float waveSum(float v) {
#pragma unroll
  for (int o = 32; o > 0; o >>= 1) v += __shfl_xor(v, o, 64);
  return v;
}
__device__ __forceinline__ float waveMax(float v) {
#pragma unroll
  for (int o = 32; o > 0; o >>= 1) v = fmaxf(v, __shfl_xor(v, o, 64));
  return v;
}
__device__ __forceinline__ float blockSum128(float v, float* s2, int t) {
  float w = waveSum(v);
  __syncthreads();
  if ((t & 63) == 0) s2[t >> 6] = w;
  __syncthreads();
  return s2[0] + s2[1];
}
__device__ __forceinline__ unsigned waveScanIncl(unsigned v, int lane) {
#pragma unroll
  for (int o = 1; o < 64; o <<= 1) {
    unsigned u = (unsigned)__shfl_up((int)v, o, 64);
    if (lane >= o) v += u;
  }
  return v;
}

// 8-row GEMV partial: a[8] accumulators, src has row stride STRIDE floats
template <int STRIDE>
__device__ __forceinline__ void gemv8(const float* src, const float* W, int j0,
                                      int cnt, int d, float* a) {
  for (int jj = 0; jj < cnt; jj += 4) {
    int j = j0 + jj;
    float w0 = W[(j + 0) * DM + d], w1 = W[(j + 1) * DM + d];
    float w2 = W[(j + 2) * DM + d], w3 = W[(j + 3) * DM + d];
#pragma unroll
    for (int rr = 0; rr < 8; ++rr) {
      float4 f = *(const float4*)(src + rr * STRIDE + j);
      a[rr] = fmaf(f.x, w0, fmaf(f.y, w1, fmaf(f.z, w2, fmaf(f.w, w3, a[rr]))));
    }
  }
}

// ---------- 1. knn ----------
__global__ __launch_bounds__(256) void knn_kernel(const float* __restrict__ xyz,
                                                  int* __restrict__ idx) {
  int row = blockIdx.x;
  int b = row >> 11, i = row & (N_PTS - 1);
  const float* xb = xyz + (size_t)b * N_PTS * 3;
  int tid = threadIdx.x;
  int lane = tid & 63, wid = tid >> 6;

  __shared__ unsigned hist[256];
  __shared__ unsigned wred[4];
  __shared__ unsigned sel[2];

  float xi = xb[i * 3 + 0], yi = xb[i * 3 + 1], zi = xb[i * 3 + 2];
  float sqi = xi * xi + yi * yi + zi * zi;

  float p[24];
  {
    const float4* xb4 = (const float4*)xb;
#pragma unroll
    for (int q = 0; q < 6; ++q) {
      float4 v = xb4[tid * 6 + q];
      p[q * 4 + 0] = v.x; p[q * 4 + 1] = v.y; p[q * 4 + 2] = v.z; p[q * 4 + 3] = v.w;
    }
  }
  unsigned key[8];
#pragma unroll
  for (int s = 0; s < 8; ++s) {
    float xj = p[s * 3 + 0], yj = p[s * 3 + 1], zj = p[s * 3 + 2];
    float d = sqi + xj * xj + yj * yj + zj * zj -
              2.0f * (xi * xj + yi * yj + zi * zj);
    unsigned u = __float_as_uint(d);
    key[s] = (u & 0x80000000u) ? ~u : (u | 0x80000000u);
  }

  unsigned prefix = 0;
  unsigned need = KNN;
  for (int shift = 24; shift >= 0; shift -= 8) {
    hist[tid] = 0;
    __syncthreads();
    if (shift == 24) {
#pragma unroll
      for (int s = 0; s < 8; ++s) {
        unsigned bin = key[s] >> 24;
        unsigned long long act = __ballot(1);
        while (act) {
          int src = __builtin_ctzll(act);
          unsigned bsel = (unsigned)__shfl((int)bin, src, 64);
          unsigned long long grp = __ballot(bin == bsel);
          if (lane == src)
            atomicAdd(&hist[bsel], (unsigned)__builtin_popcountll(grp));
          act &= ~grp;
        }
      }
    } else {
#pragma unroll
      for (int s = 0; s < 8; ++s) {
        unsigned k = key[s];
        if ((k >> (shift + 8)) == prefix)
          atomicAdd(&hist[(k >> shift) & 255u], 1u);
      }
    }
    __syncthreads();
    unsigned h = hist[tid];
    unsigned incl = waveScanIncl(h, lane);
    if (lane == 63) wred[wid] = incl;
    __syncthreads();
    unsigned offs = 0;
    for (int w = 0; w < wid; ++w) offs += wred[w];
    incl += offs;
    unsigned excl = incl - h;
    if (excl < need && need <= incl) { sel[0] = (unsigned)tid; sel[1] = need - excl; }
    __syncthreads();
    prefix = (prefix << 8) | sel[0];
    need = sel[1];
  }
  unsigned T = prefix;
  int need_eq = (int)need;

  unsigned clt = 0, ceq = 0;
#pragma unroll
  for (int s = 0; s < 8; ++s) {
    clt += (key[s] < T);
    ceq += (key[s] == T);
  }
  unsigned packed = clt | (ceq << 16);
  unsigned incl = waveScanIncl(packed, lane);
  if (lane == 63) wred[wid] = incl;
  __syncthreads();
  unsigned offs = 0;
  for (int w = 0; w < wid; ++w) offs += wred[w];
  unsigned totAll = wred[0] + wred[1] + wred[2] + wred[3];
  incl += offs;
  unsigned excl = incl - packed;
  int lt_base = (int)(excl & 0xFFFFu);
  int eq_base = (int)(excl >> 16);
  int total_lt = (int)(totAll & 0xFFFFu);

  int* orow = idx + (size_t)row * KNN;
  int lpos = 0, epos = 0;
#pragma unroll
  for (int s = 0; s < 8; ++s) {
    int j = tid * 8 + s;
    unsigned k = key[s];
    if (k < T) {
      orow[lt_base + lpos] = j; lpos++;
    } else if (k == T) {
      int r = eq_base + epos; epos++;
      if (r < need_eq) orow[total_lt + r] = j;
    }
  }
}

// ---------- 2. prep: rowsums + temb ----------
__global__ __launch_bounds__(128) void prep_kernel(
    const float* __restrict__ Wq, const float* __restrict__ bq,
    const float* __restrict__ Wk, const float* __restrict__ bk,
    const float* __restrict__ Wp2, const float* __restrict__ bp2,
    float* __restrict__ rs, float* __restrict__ ssum,
    const int* __restrict__ t, const float* __restrict__ tW1,
    const float* __restrict__ tb1, const float* __restrict__ tW2,
    const float* __restrict__ tb2, float* __restrict__ temb) {
  int blk = blockIdx.x, d = threadIdx.x;
  __shared__ float s2[2];
  __shared__ float emb[DM];
  __shared__ float h1[DM];
  if (blk < NLAYER) {
    int l = blk;
    const float* wq = Wq + (size_t)l * DM * DM;
    const float* wk = Wk + (size_t)l * DM * DM;
    const float* wp2 = Wp2 + (size_t)l * DM * DM;
    float a = 0.f, b = 0.f, c = 0.f;
    for (int j = 0; j < DM; ++j) {
      a += wq[d * DM + j];
      b += wk[d * DM + j];
      c += wp2[d * DM + j];
    }
    rs[l * 3 * DM + d] = a;
    rs[l * 3 * DM + DM + d] = b;
    rs[l * 3 * DM + 2 * DM + d] = c;
    float sq = blockSum128(bq[l * DM + d], s2, d);
    float sk = blockSum128(bk[l * DM + d], s2, d);
    float sp = blockSum128(bp2[l * DM + d], s2, d);
    if (d == 0) { ssum[l * 4 + 0] = sq; ssum[l * 4 + 1] = sk; ssum[l * 4 + 2] = sp; }
  } else {
    int b = blk - NLAYER;
    float tv = (float)t[b];
    float lg = logf(10000.0f);
    if (d < 64) {
      float f = expf(-lg * (float)d / 63.0f);
      emb[d] = sinf(tv * f);
    } else {
      float f = expf(-lg * (float)(d - 64) / 63.0f);
      emb[d] = cosf(tv * f);
    }
    __syncthreads();
    float acc = tb1[d];
    for (int j = 0; j < DM; ++j) acc = fmaf(emb[j], tW1[j * DM + d], acc);
    h1[d] = fmaxf(acc, 0.f);
    __syncthreads();
    float acc2 = tb2[d];
    for (int j = 0; j < DM; ++j) acc2 = fmaf(h1[j], tW2[j * DM + d], acc2);
    temb[b * DM + d] = acc2;
  }
}

// ---------- 3. V projection + q/k sums for layer 0 ----------
__global__ __launch_bounds__(256) void vqk_kernel(
    const float* __restrict__ feat, const float* __restrict__ Wv,
    const float* __restrict__ bv, const float* __restrict__ rs,
    const float* __restrict__ ssum, float* __restrict__ Vf,
    float* __restrict__ qsum, float* __restrict__ ksum) {
  int n0 = blockIdx.x * RBV;
  int t = threadIdx.x;
  int d = t & 127, half = t >> 7;
  __shared__ float fr[RBV][DM];
  __shared__ float part[RBV][DM];
  __shared__ float sA[2][RBV];
  __shared__ float sB[2][RBV];
#pragma unroll
  for (int u = 0; u < 2; ++u) {
    int r = half * 2 + u;
    fr[r][d] = feat[(size_t)(n0 + r) * DM + d];
  }
  __syncthreads();
  float acc[RBV] = {0.f, 0.f, 0.f, 0.f};
  int j0 = half * 64;
  for (int jj = 0; jj < 64; jj += 4) {
    int j = j0 + jj;
    float w0 = Wv[(j + 0) * DM + d], w1 = Wv[(j + 1) * DM + d];
    float w2 = Wv[(j + 2) * DM + d], w3 = Wv[(j + 3) * DM + d];
#pragma unroll
    for (int r = 0; r < RBV; ++r) {
      float4 f = *(const float4*)&fr[r][j];
      acc[r] = fmaf(f.x, w0, fmaf(f.y, w1, fmaf(f.z, w2, fmaf(f.w, w3, acc[r]))));
    }
  }
  if (half == 1) {
#pragma unroll
    for (int r = 0; r < RBV; ++r) part[r][d] = acc[r];
  }
  __syncthreads();
  if (half == 0) {
    float bvd = bv[d];
#pragma unroll
    for (int r = 0; r < RBV; ++r)
      Vf[(size_t)(n0 + r) * DM + d] = acc[r] + part[r][d] + bvd;
    int lane = t & 63, wid = (t >> 6) & 1;
    float rsq = rs[d], rsk = rs[DM + d];
#pragma unroll
    for (int r = 0; r < RBV; ++r) {
      float f = fr[r][d];
      float a = waveSum(f * rsq);
      float k = waveSum(f * rsk);
      if (lane == 0) { sA[wid][r] = a; sB[wid][r] = k; }
    }
  }
  __syncthreads();
  if (t < RBV) qsum[n0 + t] = sA[0][t] + sA[1][t] + ssum[0];
  if (t >= 64 && t < 64 + RBV) {
    int r = t - 64;
    ksum[n0 + r] = sB[0][r] + sB[1][r] + ssum[1];
  }
}

// ---------- 4. fused layer: 512 threads, 8 rows/block, wave-per-row A/B ----------
template <int LAST>
__global__ __launch_bounds__(512, 2) void fused_layer_kernel(
    const float* __restrict__ xyz, const int* __restrict__ idx,
    const float* __restrict__ fin, const float* __restrict__ Vf_in,
    const float* __restrict__ qsum_in, const float* __restrict__ ksum_in,
    const float* __restrict__ Wp1, const float* __restrict__ bp1,
    const float* __restrict__ rsL, const float* __restrict__ ssL,
    const float* __restrict__ Wp2, const float* __restrict__ bp2,
    const float* __restrict__ Wproj, const float* __restrict__ bproj,
    const float* __restrict__ gamma, int l, float* __restrict__ fout,
    const float* __restrict__ Wv_n, const float* __restrict__ bv_n,
    const float* __restrict__ rs_n, const float* __restrict__ ss_n,
    float* __restrict__ Vf_out, float* __restrict__ qsum_out,
    float* __restrict__ ksum_out,
    const float* __restrict__ x_t, const float* __restrict__ temb,
    const float* __restrict__ nW1, const float* __restrict__ nb1,
    const float* __restrict__ ng1, const float* __restrict__ nbe1,
    const float* __restrict__ nW2, const float* __restrict__ nb2,
    const float* __restrict__ ng2, const float* __restrict__ nbe2,
    const float* __restrict__ nW3, const float* __restrict__ nb3,
    float* __restrict__ out) {
  int n0 = blockIdx.x * RB8;
  int t = threadIdx.x;
  int w = t >> 6, lane = t & 63;
  int q = t >> 7, d = t & 127;
  int b = n0 >> 11;

  __shared__ float4 rel4[RB8][KNN];   // 16 KB; overlaid by part[4][8][128] after B
  __shared__ int joff[RB8][KNN];      // 4 KB
  __shared__ float hrow[RB8][DM];     // hagg -> fo
  __shared__ float zz[RB8][DM];       // vagg -> z -> LN buffers
  float* part = (float*)rel4;         // [4][8][128]

  const float* xb = xyz + (size_t)b * N_PTS * 3;

  // ---- Phase A (barrier-free): wave w owns row n0+w; lane -> k=lane, lane+64
  {
    int row = n0 + w;
    int i = row & (N_PTS - 1);
    float xi = xb[i * 3 + 0], yi = xb[i * 3 + 1], zi = xb[i * 3 + 2];
    int j1 = idx[(size_t)row * KNN + lane];
    int j2 = idx[(size_t)row * KNN + lane + 64];
    float rx1 = xi - xb[j1 * 3 + 0], ry1 = yi - xb[j1 * 3 + 1], rz1 = zi - xb[j1 * 3 + 2];
    float rx2 = xi - xb[j2 * 3 + 0], ry2 = yi - xb[j2 * 3 + 1], rz2 = zi - xb[j2 * 3 + 2];

    const float4* W1x = (const float4*)Wp1;
    const float4* W1y = (const float4*)(Wp1 + DM);
    const float4* W1z = (const float4*)(Wp1 + 2 * DM);
    const float4* Bp = (const float4*)bp1;
    const float4* W2 = (const float4*)(rsL + 2 * DM);
    float acc1 = 0.f, acc2 = 0.f;
#pragma unroll 8
    for (int qq = 0; qq < DM / 4; ++qq) {
      float4 ax = W1x[qq], ay = W1y[qq], az = W1z[qq], ab = Bp[qq], c = W2[qq];
      float hA = fmaxf(fmaf(rx1, ax.x, fmaf(ry1, ay.x, fmaf(rz1, az.x, ab.x))), 0.f);
      float hB = fmaxf(fmaf(rx1, ax.y, fmaf(ry1, ay.y, fmaf(rz1, az.y, ab.y))), 0.f);
      float hC = fmaxf(fmaf(rx1, ax.z, fmaf(ry1, ay.z, fmaf(rz1, az.z, ab.z))), 0.f);
      float hD = fmaxf(fmaf(rx1, ax.w, fmaf(ry1, ay.w, fmaf(rz1, az.w, ab.w))), 0.f);
      acc1 = fmaf(hA, c.x, fmaf(hB, c.y, fmaf(hC, c.z, fmaf(hD, c.w, acc1))));
      float hE = fmaxf(fmaf(rx2, ax.x, fmaf(ry2, ay.x, fmaf(rz2, az.x, ab.x))), 0.f);
      float hF = fmaxf(fmaf(rx2, ax.y, fmaf(ry2, ay.y, fmaf(rz2, az.y, ab.y))), 0.f);
      float hG = fmaxf(fmaf(rx2, ax.z, fmaf(ry2, ay.z, fmaf(rz2, az.z, ab.z))), 0.f);
      float hH = fmaxf(fmaf(rx2, ax.w, fmaf(ry2, ay.w, fmaf(rz2, az.w, ab.w))), 0.f);
      acc2 = fmaf(hE, c.x, fmaf(hF, c.y, fmaf(hG, c.z, fmaf(hH, c.w, acc2))));
    }
    float qs = qsum_in[row] + ssL[2];
    float l1 = qs - ksum_in[b * N_PTS + j1] + acc1;
    float l2 = qs - ksum_in[b * N_PTS + j2] + acc2;
    float m = waveMax(fmaxf(l1, l2));
    float e1 = __expf(l1 - m), e2 = __expf(l2 - m);
    float s = waveSum(e1 + e2);
    float inv = 1.0f / s;
    rel4[w][lane] = make_float4(rx1, ry1, rz1, e1 * inv);
    rel4[w][lane + 64] = make_float4(rx2, ry2, rz2, e2 * inv);
    joff[w][lane] = j1 * (DM * 4);
    joff[w][lane + 64] = j2 * (DM * 4);
  }
  __syncthreads();

  // ---- Phase B (barrier-free): wave w owns row n0+w; lane -> d=lane, lane+64
  {
    int d1 = lane, d2 = lane + 64;
    float wx1 = Wp1[d1], wy1 = Wp1[DM + d1], wz1 = Wp1[2 * DM + d1], wb1 = bp1[d1];
    float wx2 = Wp1[d2], wy2 = Wp1[DM + d2], wz2 = Wp1[2 * DM + d2], wb2 = bp1[d2];
    const char* vbase = (const char*)(Vf_in + (size_t)b * N_PTS * DM);
    const char* v1 = vbase + (size_t)d1 * 4;
    const char* v2 = vbase + (size_t)d2 * 4;
    float ha1a = 0.f, ha1b = 0.f, ha2a = 0.f, ha2b = 0.f;
    float va1a = 0.f, va1b = 0.f, va2a = 0.f, va2b = 0.f;
#pragma unroll 4
    for (int k = 0; k < KNN; k += 2) {
      float4 ra = rel4[w][k];
      float4 rb = rel4[w][k + 1];
      int ja = joff[w][k], jb = joff[w][k + 1];
      float Va1 = *(const float*)(v1 + ja);
      float Vb1 = *(const float*)(v1 + jb);
      float Va2 = *(const float*)(v2 + ja);
      float Vb2 = *(const float*)(v2 + jb);
      float hA1 = fmaxf(fmaf(ra.x, wx1, fmaf(ra.y, wy1, fmaf(ra.z, wz1, wb1))), 0.f);
      float hB1 = fmaxf(fmaf(rb.x, wx1, fmaf(rb.y, wy1, fmaf(rb.z, wz1, wb1))), 0.f);
      float hA2 = fmaxf(fmaf(ra.x, wx2, fmaf(ra.y, wy2, fmaf(ra.z, wz2, wb2))), 0.f);
      float hB2 = fmaxf(fmaf(rb.x, wx2, fmaf(rb.y, wy2, fmaf(rb.z, wz2, wb2))), 0.f);
      ha1a = fmaf(ra.w, hA1, ha1a);
      ha1b = fmaf(rb.w, hB1, ha1b);
      ha2a = fmaf(ra.w, hA2, ha2a);
      ha2b = fmaf(rb.w, hB2, ha2b);
      va1a = fmaf(ra.w, Va1, va1a);
      va1b = fmaf(rb.w, Vb1, va1b);
      va2a = fmaf(ra.w, Va2, va2a);
      va2b = fmaf(rb.w, Vb2, va2b);
    }
    hrow[w][d1] = ha1a + ha1b;
    hrow[w][d2] = ha2a + ha2b;
    zz[w][d1] = va1a + va1b;
    zz[w][d2] = va2a + va2b;
  }
  __syncthreads();

  // ---- Phase C1: z = vagg + hagg@Wp2 + bp2  (quarter-split, 8-row batch)
  {
    float a[RB8] = {0.f, 0.f, 0.f, 0.f, 0.f, 0.f, 0.f, 0.f};
    gemv8<DM>(&hrow[0][0], Wp2, q * 32, 32, d, a);
    float* pq = part + (q * RB8) * DM + d;
#pragma unroll
    for (int rr = 0; rr < RB8; ++rr) pq[rr * DM] = a[rr];
  }
  __syncthreads();
  {
    int r0 = q * 2, r1 = q * 2 + 1;
    float bpd = bp2[d];
    zz[r0][d] += part[(0 * RB8 + r0) * DM + d] + part[(1 * RB8 + r0) * DM + d] +
                 part[(2 * RB8 + r0) * DM + d] + part[(3 * RB8 + r0) * DM + d] + bpd;
    zz[r1][d] += part[(0 * RB8 + r1) * DM + d] + part[(1 * RB8 + r1) * DM + d] +
                 part[(2 * RB8 + r1) * DM + d] + part[(3 * RB8 + r1) * DM + d] + bpd;
  }
  __syncthreads();

  // ---- Phase C2: fo = fin + gamma*(z@Wproj + bproj)
  {
    float a[RB8] = {0.f, 0.f, 0.f, 0.f, 0.f, 0.f, 0.f, 0.f};
    gemv8<DM>(&zz[0][0], Wproj, q * 32, 32, d, a);
    float* pq = part + (q * RB8) * DM + d;
#pragma unroll
    for (int rr = 0; rr < RB8; ++rr) pq[rr * DM] = a[rr];
  }
  __syncthreads();
  {
    int r0 = q * 2, r1 = q * 2 + 1;
    float g = gamma[l];
    float bpr = bproj[d];
    float s0 = part[(0 * RB8 + r0) * DM + d] + part[(1 * RB8 + r0) * DM + d] +
               part[(2 * RB8 + r0) * DM + d] + part[(3 * RB8 + r0) * DM + d] + bpr;
    float s1 = part[(0 * RB8 + r1) * DM + d] + part[(1 * RB8 + r1) * DM + d] +
               part[(2 * RB8 + r1) * DM + d] + part[(3 * RB8 + r1) * DM + d] + bpr;
    float fo0 = fin[(size_t)(n0 + r0) * DM + d] + g * s0;
    float fo1 = fin[(size_t)(n0 + r1) * DM + d] + g * s1;
    if (!LAST) {
      fout[(size_t)(n0 + r0) * DM + d] = fo0;
      fout[(size_t)(n0 + r1) * DM + d] = fo1;
    }
    hrow[r0][d] = fo0;
    hrow[r1][d] = fo1;
  }
  __syncthreads();

  if constexpr (!LAST) {
    // ---- Phase D: q/k sums (wave-per-row) + next layer's V projection
    {
      int d1 = lane, d2 = lane + 64;
      float fo1 = hrow[w][d1], fo2 = hrow[w][d2];
      float qp = waveSum(fo1 * rs_n[d1] + fo2 * rs_n[d2]);
      float kp = waveSum(fo1 * rs_n[DM + d1] + fo2 * rs_n[DM + d2]);
      if (lane == 0) {
        qsum_out[n0 + w] = qp + ss_n[0];
        ksum_out[n0 + w] = kp + ss_n[1];
      }
    }
    {
      float a[RB8] = {0.f, 0.f, 0.f, 0.f, 0.f, 0.f, 0.f, 0.f};
      gemv8<DM>(&hrow[0][0], Wv_n, q * 32, 32, d, a);
      float* pq = part + (q * RB8) * DM + d;
#pragma unroll
      for (int rr = 0; rr < RB8; ++rr) pq[rr * DM] = a[rr];
    }
    __syncthreads();
    {
      int r0 = q * 2, r1 = q * 2 + 1;
      float bvd = bv_n[d];
      Vf_out[(size_t)(n0 + r0) * DM + d] =
          part[(0 * RB8 + r0) * DM + d] + part[(1 * RB8 + r0) * DM + d] +
          part[(2 * RB8 + r0) * DM + d] + part[(3 * RB8 + r0) * DM + d] + bvd;
      Vf_out[(size_t)(n0 + r1) * DM + d] =
          part[(0 * RB8 + r1) * DM + d] + part[(1 * RB8 + r1) * DM + d] +
          part[(2 * RB8 + r1) * DM + d] + part[(3 * RB8 + r1) * DM + d] + bvd;
    }
  } else {
    // ---- Head: concat -> GEMV1 -> LN1 -> GEMV2 -> LN2 -> out proj
    __shared__ float h0s[RB8][260];
    {
      int r0 = q * 2, r1 = q * 2 + 1;
#pragma unroll
      for (int rr = r0; rr <= r1; ++rr) {
        h0s[rr][3 + d] = hrow[rr][d];
        h0s[rr][131 + d] = temb[b * DM + d];
        if (d < 3) h0s[rr][d] = x_t[(size_t)(n0 + rr) * 3 + d];
        if (d == 0) h0s[rr][259] = 0.f;
      }
    }
    __syncthreads();

    // GEMV1: 259 inputs; quarter q covers [q*64, q*64+64), q==3 adds 256..258
    {
      float a[RB8] = {0.f, 0.f, 0.f, 0.f, 0.f, 0.f, 0.f, 0.f};
      gemv8<260>(&h0s[0][0], nW1, q * 64, 64, d, a);
      if (q == 3) {
        for (int j = 256; j < 259; ++j) {
          float wv = nW1[j * DM + d];
#pragma unroll
          for (int rr = 0; rr < RB8; ++rr) a[rr] = fmaf(h0s[rr][j], wv, a[rr]);
        }
      }
      float* pq = part + (q * RB8) * DM + d;
#pragma unroll
      for (int rr = 0; rr < RB8; ++rr) pq[rr * DM] = a[rr];
    }
    __syncthreads();
    {
      int r0 = q * 2, r1 = q * 2 + 1;
      float nb = nb1[d];
      zz[r0][d] = nb + part[(0 * RB8 + r0) * DM + d] + part[(1 * RB8 + r0) * DM + d] +
                  part[(2 * RB8 + r0) * DM + d] + part[(3 * RB8 + r0) * DM + d];
      zz[r1][d] = nb + part[(0 * RB8 + r1) * DM + d] + part[(1 * RB8 + r1) * DM + d] +
                  part[(2 * RB8 + r1) * DM + d] + part[(3 * RB8 + r1) * DM + d];
    }
    __syncthreads();
    // LN1 per wave (row w)
    {
      int d1 = lane, d2 = lane + 64;
      float x1 = zz[w][d1], x2 = zz[w][d2];
      float s1 = waveSum(x1 + x2);
      float sq = waveSum(x1 * x1 + x2 * x2);
      float m = s1 * (1.0f / 128.0f);
      float var = sq * (1.0f / 128.0f) - m * m;
      float rstd = rsqrtf(var + EPSLN);
      float y1 = fmaxf((x1 - m) * rstd * ng1[d1] + nbe1[d1], 0.f);
      float y2 = fmaxf((x2 - m) * rstd * ng1[d2] + nbe1[d2], 0.f);
      zz[w][d1] = y1;
      zz[w][d2] = y2;
    }
    __syncthreads();
    // GEMV2: quarter q covers [q*32, q*32+32)
    {
      float a[RB8] = {0.f, 0.f, 0.f, 0.f, 0.f, 0.f, 0.f, 0.f};
      gemv8<DM>(&zz[0][0], nW2, q * 32, 32, d, a);
      float* pq = part + (q * RB8) * DM + d;
#pragma unroll
      for (int rr = 0; rr < RB8; ++rr) pq[rr * DM] = a[rr];
    }
    __syncthreads();
    {
      int r0 = q * 2, r1 = q * 2 + 1;
      float nb = nb2[d];
      hrow[r0][d] = nb + part[(0 * RB8 + r0) * DM + d] + part[(1 * RB8 + r0) * DM + d] +
                    part[(2 * RB8 + r0) * DM + d] + part[(3 * RB8 + r0) * DM + d];
      hrow[r1][d] = nb + part[(0 * RB8 + r1) * DM + d] + part[(1 * RB8 + r1) * DM + d] +
                    part[(2 * RB8 + r1) * DM + d] + part[(3 * RB8 + r1) * DM + d];
    }
    __syncthreads();
    // LN2 + 128->3 projection per wave (row w)
    {
      int d1 = lane, d2 = lane + 64;
      float x1 = hrow[w][d1], x2 = hrow[w][d2];
      float s1 = waveSum(x1 + x2);
      float sq = waveSum(x1 * x1 + x2 * x2);
      float m = s1 * (1.0f / 128.0f);
      float var = sq * (1.0f / 128.0f) - m * m;
      float rstd = rsqrtf(var + EPSLN);
      float y1 = fmaxf((x1 - m) * rstd * ng2[d1] + nbe2[d1], 0.f);
      float y2 = fmaxf((x2 - m) * rstd * ng2[d2] + nbe2[d2], 0.f);
      float p0 = waveSum(y1 * nW3[d1 * 3 + 0] + y2 * nW3[d2 * 3 + 0]);
      float p1 = waveSum(y1 * nW3[d1 * 3 + 1] + y2 * nW3[d2 * 3 + 1]);
      float p2 = waveSum(y1 * nW3[d1 * 3 + 2] + y2 * nW3[d2 * 3 + 2]);
      if (lane == 0) {
        out[(size_t)(n0 + w) * 3 + 0] = p0 + nb3[0];
        out[(size_t)(n0 + w) * 3 + 1] = p1 + nb3[1];
        out[(size_t)(n0 + w) * 3 + 2] = p2 + nb3[2];
      }
    }
  }
}

// ---------- launch ----------
extern "C" void kernel_launch(void* const* d_in, const int* in_sizes, int n_in,
                              void* d_out, int out_size, void* d_ws,
                              size_t ws_size, hipStream_t stream) {
  const float* xyz = (const float*)d_in[0];
  const float* feat = (const float*)d_in[1];
  const float* x_t = (const float*)d_in[2];
  const int* t = (const int*)d_in[3];
  const float* Wq = (const float*)d_in[4];
  const float* bq = (const float*)d_in[5];
  const float* Wk = (const float*)d_in[6];
  const float* bk = (const float*)d_in[7];
  const float* Wv = (const float*)d_in[8];
  const float* bv = (const float*)d_in[9];
  const float* Wp1 = (const float*)d_in[10];
  const float* bp1 = (const float*)d_in[11];
  const float* Wp2 = (const float*)d_in[12];
  const float* bp2 = (const float*)d_in[13];
  const float* gamma = (const float*)d_in[14];
  const float* Wproj = (const float*)d_in[15];
  const float* bproj = (const float*)d_in[16];
  const float* tW1 = (const float*)d_in[17];
  const float* tb1 = (const float*)d_in[18];
  const float* tW2 = (const float*)d_in[19];
  const float* tb2 = (const float*)d_in[20];
  const float* nW1 = (const float*)d_in[21];
  const float* nb1 = (const float*)d_in[22];
  const float* ng1 = (const float*)d_in[23];
  const float* nbe1 = (const float*)d_in[24];
  const float* nW2 = (const float*)d_in[25];
  const float* nb2 = (const float*)d_in[26];
  const float* ng2 = (const float*)d_in[27];
  const float* nbe2 = (const float*)d_in[28];
  const float* nW3 = (const float*)d_in[29];
  const float* nb3 = (const float*)d_in[30];
  float* out = (float*)d_out;

  char* ws = (char*)d_ws;
  size_t off = 0;
  int* w_idx = (int*)(ws + off); off += (size_t)ROWS * KNN * 4;
  float* w_VfA = (float*)(ws + off); off += (size_t)ROWS * DM * 4;
  float* w_VfB = (float*)(ws + off); off += (size_t)ROWS * DM * 4;
  float* w_qsA = (float*)(ws + off); off += (size_t)ROWS * 4;
  float* w_ksA = (float*)(ws + off); off += (size_t)ROWS * 4;
  float* w_qsB = (float*)(ws + off); off += (size_t)ROWS * 4;
  float* w_ksB = (float*)(ws + off); off += (size_t)ROWS * 4;
  float* w_fA = (float*)(ws + off); off += (size_t)ROWS * DM * 4;
  float* w_fB = (float*)(ws + off); off += (size_t)ROWS * DM * 4;
  float* w_temb = (float*)(ws + off); off += (size_t)B_SZ * DM * 4;
  float* w_rs = (float*)(ws + off); off += (size_t)NLAYER * 3 * DM * 4;
  float* w_ssum = (float*)(ws + off); off += (size_t)NLAYER * 4 * 4;

  knn_kernel<<<ROWS, 256, 0, stream>>>(xyz, w_idx);
  prep_kernel<<<NLAYER + B_SZ, 128, 0, stream>>>(Wq, bq, Wk, bk, Wp2, bp2,
                                                 w_rs, w_ssum, t, tW1, tb1,
                                                 tW2, tb2, w_temb);
  vqk_kernel<<<ROWS / RBV, 256, 0, stream>>>(feat, Wv, bv, w_rs, w_ssum,
                                             w_VfA, w_qsA, w_ksA);

  const float* fins[4] = {feat, w_fA, w_fB, w_fA};
  float* fouts[4] = {w_fA, w_fB, w_fA, w_fB};
  const float* VfIn[4] = {w_VfA, w_VfB, w_VfA, w_VfB};
  float* VfOut[4] = {w_VfB, w_VfA, w_VfB, w_VfA};
  const float* qsIn[4] = {w_qsA, w_qsB, w_qsA, w_qsB};
  float* qsOut[4] = {w_qsB, w_qsA, w_qsB, w_qsA};
  const float* ksIn[4] = {w_ksA, w_ksB, w_ksA, w_ksB};
  float* ksOut[4] = {w_ksB, w_ksA, w_ksB, w_ksA};

  for (int l = 0; l < NLAYER; ++l) {
    const float* rsL = w_rs + (size_t)l * 3 * DM;
    const float* ssL = w_ssum + (size_t)l * 4;
    int ln = (l + 1 < NLAYER) ? (l + 1) : l;
    const float* rsN = w_rs + (size_t)ln * 3 * DM;
    const float* ssN = w_ssum + (size_t)ln * 4;
    if (l < NLAYER - 1) {
      fused_layer_kernel<0><<<ROWS / RB8, 512, 0, stream>>>(
          xyz, w_idx, fins[l], VfIn[l], qsIn[l], ksIn[l],
          Wp1 + (size_t)l * 3 * DM, bp1 + (size_t)l * DM, rsL, ssL,
          Wp2 + (size_t)l * DM * DM, bp2 + (size_t)l * DM,
          Wproj + (size_t)l * DM * DM, bproj + (size_t)l * DM, gamma, l,
          fouts[l], Wv + (size_t)ln * DM * DM, bv + (size_t)ln * DM, rsN, ssN,
          VfOut[l], qsOut[l], ksOut[l], x_t, w_temb, nW1, nb1, ng1, nbe1, nW2,
          nb2, ng2, nbe2, nW3, nb3, out);
    } else {
      fused_layer_kernel<1><<<ROWS / RB8, 512, 0, stream>>>(
          xyz, w_idx, fins[l], VfIn[l], qsIn[l], ksIn[l],
          Wp1 + (size_t)l * 3 * DM, bp1 + (size_t)l * DM, rsL, ssL,
          Wp2 + (size_t)l * DM * DM, bp2 + (size_t)l * DM,
          Wproj + (size_t)l * DM * DM, bproj + (size_t)l * DM, gamma, l,
          fouts[l], Wv + (size_t)ln * DM * DM, bv + (size_t)ln * DM, rsN, ssN,
          VfOut[l], qsOut[l], ksOut[l], x_t, w_temb, nW1, nb1, ng1, nbe1, nW2,
          nb2, ng2, nbe2, nW3, nb3, out);
    }
  }
}